// Round 1
// baseline (1181.614 us; speedup 1.0000x reference)
//
#include <hip/hip_runtime.h>
#include <math.h>

#define B_  128
#define N_  21
#define D_  300
#define H_  128
#define H2_ 256
#define NP  24   // padded N for transposed LDS rows (16B-aligned rows)

__device__ __forceinline__ float lrelu(float v) { return v > 0.f ? v : 0.01f * v; }

// One block per (b,i) row: computes adj[b,i,:] through the 4-stage MLP,
// top-5 masks it, writes A row.
__global__ __launch_bounds__(256) void edge_kernel(
    const float* __restrict__ x,
    const float* __restrict__ w0, const float* __restrict__ w1,
    const float* __restrict__ w2, const float* __restrict__ wo,
    const float* __restrict__ bo, float* __restrict__ A)
{
    const int b = blockIdx.x / N_;
    const int i = blockIdx.x - b * N_;
    const int tid = threadIdx.x;

    __shared__ float s_h0[H2_][NP];                 // 24576 B, h0 transposed [c][j]
    __shared__ union {
        float xij[D_][NP];                          // 28800 B, xij transposed [d][j]
        struct { float h1[H_][NP]; float h2[H_][NP]; } hh;  // 24576 B
    } u;
    __shared__ float s_adj[N_ + 1];
    __shared__ float s_mask[N_ + 1];

    const float* xb = x + (size_t)b * N_ * D_;
    const float* xi = xb + (size_t)i * D_;

    // stage xij[d][j] = exp(-|x[b,i,d] - x[b,j,d]|)
    for (int it = tid; it < N_ * D_; it += 256) {
        int j = it / D_;
        int d = it - j * D_;
        u.xij[d][j] = expf(-fabsf(xb[(size_t)j * D_ + d] - xi[d]));
    }
    // zero the pad columns so padded accumulators stay 0
    for (int it = tid; it < D_ * (NP - N_); it += 256) {
        int d = it / (NP - N_);
        int j = N_ + (it - d * (NP - N_));
        u.xij[d][j] = 0.f;
    }
    __syncthreads();

    // GEMM1: h0[c][j] = lrelu(sum_d w0[c,d] * xij[d][j]);  c = tid (256 channels)
    {
        float acc[NP];
        #pragma unroll
        for (int j = 0; j < NP; ++j) acc[j] = 0.f;
        const float* w0r = w0 + (size_t)tid * D_;
        for (int d = 0; d < D_; d += 4) {
            float4 wv = *(const float4*)(w0r + d);
            #pragma unroll
            for (int dd = 0; dd < 4; ++dd) {
                float w = (dd == 0) ? wv.x : (dd == 1) ? wv.y : (dd == 2) ? wv.z : wv.w;
                #pragma unroll
                for (int j4 = 0; j4 < NP; j4 += 4) {
                    float4 xv = *(const float4*)(&u.xij[d + dd][j4]);
                    acc[j4 + 0] += w * xv.x;
                    acc[j4 + 1] += w * xv.y;
                    acc[j4 + 2] += w * xv.z;
                    acc[j4 + 3] += w * xv.w;
                }
            }
        }
        #pragma unroll
        for (int j = 0; j < NP; ++j) s_h0[tid][j] = lrelu(acc[j]);
    }
    __syncthreads();

    // GEMM2: h1[o][j] = lrelu(sum_c w1[o,c] * h0[c][j]);  o = tid < 128
    if (tid < H_) {
        float acc[NP];
        #pragma unroll
        for (int j = 0; j < NP; ++j) acc[j] = 0.f;
        const float* w1r = w1 + (size_t)tid * H2_;
        for (int c = 0; c < H2_; c += 4) {
            float4 wv = *(const float4*)(w1r + c);
            #pragma unroll
            for (int cc = 0; cc < 4; ++cc) {
                float w = (cc == 0) ? wv.x : (cc == 1) ? wv.y : (cc == 2) ? wv.z : wv.w;
                #pragma unroll
                for (int j4 = 0; j4 < NP; j4 += 4) {
                    float4 xv = *(const float4*)(&s_h0[c + cc][j4]);
                    acc[j4 + 0] += w * xv.x;
                    acc[j4 + 1] += w * xv.y;
                    acc[j4 + 2] += w * xv.z;
                    acc[j4 + 3] += w * xv.w;
                }
            }
        }
        #pragma unroll
        for (int j = 0; j < NP; ++j) u.hh.h1[tid][j] = lrelu(acc[j]);
    }
    __syncthreads();

    // GEMM3: h2[o][j] = lrelu(sum_c w2[o,c] * h1[c][j]);  o = tid < 128
    if (tid < H_) {
        float acc[NP];
        #pragma unroll
        for (int j = 0; j < NP; ++j) acc[j] = 0.f;
        const float* w2r = w2 + (size_t)tid * H_;
        for (int c = 0; c < H_; c += 4) {
            float4 wv = *(const float4*)(w2r + c);
            #pragma unroll
            for (int cc = 0; cc < 4; ++cc) {
                float w = (cc == 0) ? wv.x : (cc == 1) ? wv.y : (cc == 2) ? wv.z : wv.w;
                #pragma unroll
                for (int j4 = 0; j4 < NP; j4 += 4) {
                    float4 xv = *(const float4*)(&u.hh.h1[c + cc][j4]);
                    acc[j4 + 0] += w * xv.x;
                    acc[j4 + 1] += w * xv.y;
                    acc[j4 + 2] += w * xv.z;
                    acc[j4 + 3] += w * xv.w;
                }
            }
        }
        #pragma unroll
        for (int j = 0; j < NP; ++j) u.hh.h2[tid][j] = lrelu(acc[j]);
    }
    __syncthreads();

    // sim + sigmoid; zero diagonal
    if (tid < N_) {
        float s = 0.f;
        for (int c = 0; c < H_; ++c) s += u.hh.h2[c][tid] * wo[c];
        s += bo[0];
        float a = 1.f / (1.f + expf(-s));
        if (tid == i) a = 0.f;
        s_adj[tid] = a;
    }
    __syncthreads();

    // top-5 (lax.top_k tie-break: lowest index wins -> strict > on ascending scan)
    if (tid == 0) {
        unsigned used = 0;
        for (int r = 0; r < 5; ++r) {
            float best = -1.f; int bi = 0;
            for (int j = 0; j < N_; ++j) {
                if (used & (1u << j)) continue;
                if (s_adj[j] > best) { best = s_adj[j]; bi = j; }
            }
            used |= (1u << bi);
        }
        for (int j = 0; j < N_; ++j) s_mask[j] = ((used >> j) & 1u) ? 1.f : 0.f;
    }
    __syncthreads();

    if (tid < N_) A[(size_t)blockIdx.x * N_ + tid] = s_adj[tid] * s_mask[tid];
}

// neigh[b,s,:] = x[b,s,:] @ wn^T + bn  — one block per (b,s)
__global__ __launch_bounds__(256) void neigh_kernel(
    const float* __restrict__ x, const float* __restrict__ wn,
    const float* __restrict__ bn, float* __restrict__ neigh)
{
    const int bs = blockIdx.x;
    const int tid = threadIdx.x;
    __shared__ float sx[D_ + 4];
    const float* xr = x + (size_t)bs * D_;
    for (int d = tid; d < D_; d += 256) sx[d] = xr[d];
    __syncthreads();
    for (int o = tid; o < D_; o += 256) {
        float acc = bn[o];
        const float* wrow = wn + (size_t)o * D_;
        for (int k = 0; k < D_; k += 4) {
            float4 wv = *(const float4*)(wrow + k);
            float4 xv = *(const float4*)(&sx[k]);
            acc += wv.x * xv.x + wv.y * xv.y + wv.z * xv.z + wv.w * xv.w;
        }
        neigh[(size_t)bs * D_ + o] = acc;
    }
}

// out[b,t,:] = lrelu((A[b,t,:]@neigh[b] + rowsum(A)*e0)/5 + x[b,t,:]@wr^T + br)
__global__ __launch_bounds__(256) void combine_kernel(
    const float* __restrict__ x, const float* __restrict__ A,
    const float* __restrict__ neigh, const float* __restrict__ wr,
    const float* __restrict__ br, const float* __restrict__ eemb,
    float* __restrict__ out)
{
    const int bt = blockIdx.x;
    const int b = bt / N_;
    const int tid = threadIdx.x;
    __shared__ float sx[D_ + 4];
    __shared__ float sArow[N_ + 1];
    __shared__ float srs;
    const float* xr = x + (size_t)bt * D_;
    for (int d = tid; d < D_; d += 256) sx[d] = xr[d];
    if (tid < N_) sArow[tid] = A[(size_t)bt * N_ + tid];
    __syncthreads();
    if (tid == 0) {
        float s = 0.f;
        #pragma unroll
        for (int j = 0; j < N_; ++j) s += sArow[j];
        srs = s;
    }
    __syncthreads();
    const float* e0 = eemb;  // row 0 of [4, D]
    const float* nb = neigh + (size_t)b * N_ * D_;
    for (int o = tid; o < D_; o += 256) {
        float acc = br[o];
        const float* wrow = wr + (size_t)o * D_;
        for (int k = 0; k < D_; k += 4) {
            float4 wv = *(const float4*)(wrow + k);
            float4 xv = *(const float4*)(&sx[k]);
            acc += wv.x * xv.x + wv.y * xv.y + wv.z * xv.z + wv.w * xv.w;
        }
        float m = srs * e0[o];
        #pragma unroll
        for (int s2 = 0; s2 < N_; ++s2) m += sArow[s2] * nb[(size_t)s2 * D_ + o];
        out[(size_t)bt * D_ + o] = lrelu(m / 5.0f + acc);
    }
}

extern "C" void kernel_launch(void* const* d_in, const int* in_sizes, int n_in,
                              void* d_out, int out_size, void* d_ws, size_t ws_size,
                              hipStream_t stream)
{
    const float* x0 = (const float*)d_in[0];
    auto L = [&](int l, int k) { return (const float*)d_in[1 + l * 10 + k]; };

    float* A     = (float*)d_ws;                          // 2688*21*4   = 225,792 B
    float* neigh = (float*)((char*)d_ws + (1 << 18));     // 806400*4    = 3,225,600 B
    float* x1    = (float*)d_out;                         // layer-1 output lives in d_out

    for (int l = 0; l < 2; ++l) {
        const float* xin = (l == 0) ? x0 : x1;
        edge_kernel<<<B_ * N_, 256, 0, stream>>>(xin, L(l, 0), L(l, 1), L(l, 2),
                                                 L(l, 3), L(l, 4), A);
        neigh_kernel<<<B_ * N_, 256, 0, stream>>>(xin, L(l, 5), L(l, 6), neigh);
        combine_kernel<<<B_ * N_, 256, 0, stream>>>(xin, A, neigh, L(l, 7),
                                                    L(l, 8), L(l, 9), x1);
    }
}

// Round 2
// 1155.393 us; speedup vs baseline: 1.0227x; 1.0227x over previous
//
#include <hip/hip_runtime.h>
#include <math.h>

#define B_  128
#define N_  21
#define D_  300
#define H_  128
#define H2_ 256
#define NP  24   // padded N (16B-aligned rows)

__device__ __forceinline__ float lrelu(float v) { return v > 0.f ? v : 0.01f * v; }

// ---------------------------------------------------------------------------
// x [B][N][D] -> xT [B][D][N] (per-b transpose), linear coalesced writes
__global__ __launch_bounds__(256) void xpose_kernel(
    const float* __restrict__ x, float* __restrict__ xT)
{
    const int b = blockIdx.x;
    const float* xb = x + (size_t)b * N_ * D_;
    float* xtb = xT + (size_t)b * N_ * D_;
    for (int it = threadIdx.x; it < N_ * D_; it += 256) {
        int d = it / N_, i2 = it - d * N_;
        xtb[it] = xb[(size_t)i2 * D_ + d];
    }
}

// ---------------------------------------------------------------------------
// One block per (b,i): full edge MLP -> top-5 masked A row.
// All LDS reads in the GEMMs are wave-uniform broadcasts; staging writes are
// linear (conflict-free). Register tiles: G1 2c x 12j, G2/G3 2o x 6j.
__global__ __launch_bounds__(256, 4) void edge_kernel(
    const float* __restrict__ xT,
    const float* __restrict__ w0, const float* __restrict__ w1,
    const float* __restrict__ w2, const float* __restrict__ wo,
    const float* __restrict__ bo, float* __restrict__ A)
{
    const int b = blockIdx.x / N_;
    const int i = blockIdx.x - b * N_;
    const int tid = threadIdx.x;

    __shared__ union { float xc[100][NP]; float h1[H_][NP]; } RA;   // 12.3 KB
    __shared__ union { float h0[H2_][NP]; float h2[H_][NP]; } RB;   // 24.6 KB
    __shared__ float s_wo[H_];
    __shared__ float s_adj[32];
    __shared__ unsigned s_used;

    const float* xTb = xT + (size_t)b * D_ * N_;

    if (tid < H_) s_wo[tid] = wo[tid];

    // ---------------- GEMM1: h0[c][j], c-pair x j-half per thread ----------
    const int cp = tid & 127;        // channels 2cp, 2cp+1
    const int jh = tid >> 7;         // j block of 12
    const int j0 = jh * 12;
    float acc0[12], acc1[12];
    #pragma unroll
    for (int q = 0; q < 12; ++q) { acc0[q] = 0.f; acc1[q] = 0.f; }
    const float* w0a = w0 + (size_t)(2 * cp) * D_;
    const float* w0b = w0a + D_;

    for (int ch = 0; ch < 3; ++ch) {
        const int d0 = ch * 100;
        __syncthreads();   // previous chunk fully consumed
        for (int it = tid; it < 100 * NP; it += 256) {
            int d = it / NP, j = it - d * NP;
            float v = 0.f;
            if (j < N_) {
                float xa = xTb[(size_t)(d0 + d) * N_ + j];
                float xc = xTb[(size_t)(d0 + d) * N_ + i];
                v = expf(-fabsf(xa - xc));
            }
            RA.xc[d][j] = v;   // address == it : conflict-free
        }
        __syncthreads();
        for (int d4 = 0; d4 < 100; d4 += 4) {
            float4 wa = *(const float4*)(w0a + d0 + d4);
            float4 wb = *(const float4*)(w0b + d0 + d4);
            #pragma unroll
            for (int dd = 0; dd < 4; ++dd) {
                float wA = (&wa.x)[dd], wB = (&wb.x)[dd];
                const float* xr = &RA.xc[d4 + dd][j0];
                float4 x0 = *(const float4*)(xr);
                float4 x1 = *(const float4*)(xr + 4);
                float4 x2 = *(const float4*)(xr + 8);
                #pragma unroll
                for (int q = 0; q < 4; ++q) {
                    float xv = (&x0.x)[q];
                    acc0[q] += wA * xv; acc1[q] += wB * xv;
                }
                #pragma unroll
                for (int q = 0; q < 4; ++q) {
                    float xv = (&x1.x)[q];
                    acc0[4 + q] += wA * xv; acc1[4 + q] += wB * xv;
                }
                #pragma unroll
                for (int q = 0; q < 4; ++q) {
                    float xv = (&x2.x)[q];
                    acc0[8 + q] += wA * xv; acc1[8 + q] += wB * xv;
                }
            }
        }
    }
    __syncthreads();
    {   // vectorized h0 writes
        float4 t0, t1, t2;
        #pragma unroll
        for (int q = 0; q < 4; ++q) { (&t0.x)[q] = lrelu(acc0[q]);
                                      (&t1.x)[q] = lrelu(acc0[4+q]);
                                      (&t2.x)[q] = lrelu(acc0[8+q]); }
        *(float4*)&RB.h0[2*cp][j0]     = t0;
        *(float4*)&RB.h0[2*cp][j0+4]   = t1;
        *(float4*)&RB.h0[2*cp][j0+8]   = t2;
        #pragma unroll
        for (int q = 0; q < 4; ++q) { (&t0.x)[q] = lrelu(acc1[q]);
                                      (&t1.x)[q] = lrelu(acc1[4+q]);
                                      (&t2.x)[q] = lrelu(acc1[8+q]); }
        *(float4*)&RB.h0[2*cp+1][j0]   = t0;
        *(float4*)&RB.h0[2*cp+1][j0+4] = t1;
        *(float4*)&RB.h0[2*cp+1][j0+8] = t2;
    }
    __syncthreads();

    // ---------------- GEMM2: h1[o][j] = lrelu(w1 @ h0), K=256 --------------
    const int op = tid & 63;        // rows 2op, 2op+1
    const int jq = tid >> 6;        // j block of 6
    const int j1 = jq * 6;
    float b0[6], b1[6];
    #pragma unroll
    for (int q = 0; q < 6; ++q) { b0[q] = 0.f; b1[q] = 0.f; }
    {
        const float* w1a = w1 + (size_t)(2 * op) * H2_;
        const float* w1b = w1a + H2_;
        for (int c4 = 0; c4 < H2_; c4 += 4) {
            float4 wa = *(const float4*)(w1a + c4);
            float4 wb = *(const float4*)(w1b + c4);
            #pragma unroll
            for (int cc = 0; cc < 4; ++cc) {
                float wA = (&wa.x)[cc], wB = (&wb.x)[cc];
                const float* hr = &RB.h0[c4 + cc][j1];
                float2 h0v = *(const float2*)(hr);
                float2 h1v = *(const float2*)(hr + 2);
                float2 h2v = *(const float2*)(hr + 4);
                b0[0] += wA * h0v.x; b1[0] += wB * h0v.x;
                b0[1] += wA * h0v.y; b1[1] += wB * h0v.y;
                b0[2] += wA * h1v.x; b1[2] += wB * h1v.x;
                b0[3] += wA * h1v.y; b1[3] += wB * h1v.y;
                b0[4] += wA * h2v.x; b1[4] += wB * h2v.x;
                b0[5] += wA * h2v.y; b1[5] += wB * h2v.y;
            }
        }
    }
    // h1 goes to RA (xc dead since GEMM1 done); readers sync below
    {
        float2 t;
        t.x = lrelu(b0[0]); t.y = lrelu(b0[1]); *(float2*)&RA.h1[2*op][j1]   = t;
        t.x = lrelu(b0[2]); t.y = lrelu(b0[3]); *(float2*)&RA.h1[2*op][j1+2] = t;
        t.x = lrelu(b0[4]); t.y = lrelu(b0[5]); *(float2*)&RA.h1[2*op][j1+4] = t;
        t.x = lrelu(b1[0]); t.y = lrelu(b1[1]); *(float2*)&RA.h1[2*op+1][j1]   = t;
        t.x = lrelu(b1[2]); t.y = lrelu(b1[3]); *(float2*)&RA.h1[2*op+1][j1+2] = t;
        t.x = lrelu(b1[4]); t.y = lrelu(b1[5]); *(float2*)&RA.h1[2*op+1][j1+4] = t;
    }
    __syncthreads();

    // ---------------- GEMM3: h2[o][j] = lrelu(w2 @ h1), K=128 --------------
    float c0[6], c1[6];
    #pragma unroll
    for (int q = 0; q < 6; ++q) { c0[q] = 0.f; c1[q] = 0.f; }
    {
        const float* w2a = w2 + (size_t)(2 * op) * H_;
        const float* w2b = w2a + H_;
        for (int c4 = 0; c4 < H_; c4 += 4) {
            float4 wa = *(const float4*)(w2a + c4);
            float4 wb = *(const float4*)(w2b + c4);
            #pragma unroll
            for (int cc = 0; cc < 4; ++cc) {
                float wA = (&wa.x)[cc], wB = (&wb.x)[cc];
                const float* hr = &RA.h1[c4 + cc][j1];
                float2 h0v = *(const float2*)(hr);
                float2 h1v = *(const float2*)(hr + 2);
                float2 h2v = *(const float2*)(hr + 4);
                c0[0] += wA * h0v.x; c1[0] += wB * h0v.x;
                c0[1] += wA * h0v.y; c1[1] += wB * h0v.y;
                c0[2] += wA * h1v.x; c1[2] += wB * h1v.x;
                c0[3] += wA * h1v.y; c1[3] += wB * h1v.y;
                c0[4] += wA * h2v.x; c1[4] += wB * h2v.x;
                c0[5] += wA * h2v.y; c1[5] += wB * h2v.y;
            }
        }
    }
    __syncthreads();   // all h0 reads done before overwriting RB with h2
    {
        float2 t;
        t.x = lrelu(c0[0]); t.y = lrelu(c0[1]); *(float2*)&RB.h2[2*op][j1]   = t;
        t.x = lrelu(c0[2]); t.y = lrelu(c0[3]); *(float2*)&RB.h2[2*op][j1+2] = t;
        t.x = lrelu(c0[4]); t.y = lrelu(c0[5]); *(float2*)&RB.h2[2*op][j1+4] = t;
        t.x = lrelu(c1[0]); t.y = lrelu(c1[1]); *(float2*)&RB.h2[2*op+1][j1]   = t;
        t.x = lrelu(c1[2]); t.y = lrelu(c1[3]); *(float2*)&RB.h2[2*op+1][j1+2] = t;
        t.x = lrelu(c1[4]); t.y = lrelu(c1[5]); *(float2*)&RB.h2[2*op+1][j1+4] = t;
    }
    __syncthreads();

    // ---------------- sim -> sigmoid -> diag -> top-5 ----------------------
    if (tid < N_) {
        float s = 0.f;
        for (int c = 0; c < H_; ++c) s += RB.h2[c][tid] * s_wo[c];
        s += bo[0];
        float a = 1.f / (1.f + expf(-s));
        if (tid == i) a = 0.f;
        s_adj[tid] = a;
    }
    __syncthreads();
    if (tid == 0) {
        unsigned used = 0;
        for (int r = 0; r < 5; ++r) {
            float best = -1.f; int bi = 0;
            for (int j = 0; j < N_; ++j) {
                if (used & (1u << j)) continue;
                if (s_adj[j] > best) { best = s_adj[j]; bi = j; }
            }
            used |= (1u << bi);
        }
        s_used = used;
    }
    __syncthreads();
    if (tid < N_)
        A[(size_t)blockIdx.x * N_ + tid] = ((s_used >> tid) & 1u) ? s_adj[tid] : 0.f;
}

// ---------------------------------------------------------------------------
// One block per b: fused node update.
//   neigh = x@wn^T+bn and r = x@wr^T+br accumulated in registers over k,
//   then msg[t] = (A[t,:]@neigh + rs_t*(bn_o+e0_o))/5, out = lrelu(msg + r).
// Writes either out [B,N,D] (last layer) or xT for the next layer.
__global__ __launch_bounds__(320) void node_kernel(
    const float* __restrict__ xT, const float* __restrict__ A,
    const float* __restrict__ wn, const float* __restrict__ bn,
    const float* __restrict__ wr, const float* __restrict__ br,
    const float* __restrict__ eemb,
    float* __restrict__ out, float* __restrict__ xTout, int write_xT)
{
    const int b = blockIdx.x;
    const int tid = threadIdx.x;
    __shared__ float sxT[D_][NP];    // 28.8 KB
    __shared__ float sA[N_][NP];
    __shared__ float srs[N_];

    const float* xTb = xT + (size_t)b * D_ * N_;
    for (int it = tid; it < D_ * NP; it += 320) {
        int d = it / NP, j = it - d * NP;
        sxT[d][j] = (j < N_) ? xTb[(size_t)d * N_ + j] : 0.f;
    }
    for (int it = tid; it < N_ * N_; it += 320) {
        int t = it / N_, s = it - t * N_;
        sA[t][s] = A[((size_t)b * N_ + t) * N_ + s];
    }
    __syncthreads();
    if (tid < N_) {
        float s = 0.f;
        #pragma unroll
        for (int j = 0; j < N_; ++j) s += sA[tid][j];
        srs[tid] = s;
    }
    __syncthreads();

    const int o = tid;
    if (o < D_) {
        float nacc[NP], racc[NP];
        #pragma unroll
        for (int j = 0; j < NP; ++j) { nacc[j] = 0.f; racc[j] = 0.f; }
        const float* wnr = wn + (size_t)o * D_;
        const float* wrr = wr + (size_t)o * D_;
        for (int k4 = 0; k4 < D_; k4 += 4) {
            float4 wnv = *(const float4*)(wnr + k4);
            float4 wrv = *(const float4*)(wrr + k4);
            #pragma unroll
            for (int kk = 0; kk < 4; ++kk) {
                float wN = (&wnv.x)[kk], wR = (&wrv.x)[kk];
                const float* xr = &sxT[k4 + kk][0];
                #pragma unroll
                for (int j4 = 0; j4 < 6; ++j4) {
                    float4 xv = *(const float4*)(xr + j4 * 4);
                    #pragma unroll
                    for (int q = 0; q < 4; ++q) {
                        float x = (&xv.x)[q];
                        nacc[j4 * 4 + q] += wN * x;
                        racc[j4 * 4 + q] += wR * x;
                    }
                }
            }
        }
        const float bn_o = bn[o], br_o = br[o], e0_o = eemb[o];
        #pragma unroll 1
        for (int t = 0; t < N_; ++t) {
            float m = 0.f;
            #pragma unroll
            for (int s = 0; s < N_; ++s) m += sA[t][s] * nacc[s];
            float val = lrelu((m + srs[t] * (bn_o + e0_o)) * 0.2f + racc[t] + br_o);
            if (write_xT) xTout[(size_t)b * D_ * N_ + (size_t)o * N_ + t] = val;
            else          out[((size_t)b * N_ + t) * D_ + o] = val;
        }
    }
}

// ---------------------------------------------------------------------------
extern "C" void kernel_launch(void* const* d_in, const int* in_sizes, int n_in,
                              void* d_out, int out_size, void* d_ws, size_t ws_size,
                              hipStream_t stream)
{
    const float* x0 = (const float*)d_in[0];
    auto L = [&](int l, int k) { return (const float*)d_in[1 + l * 10 + k]; };

    float* A  = (float*)d_ws;                        // 2688*21*4 = 225,792 B
    float* xT = (float*)((char*)d_ws + (1 << 18));   // 128*300*21*4 = 3,225,600 B

    xpose_kernel<<<B_, 256, 0, stream>>>(x0, xT);
    for (int l = 0; l < 2; ++l) {
        edge_kernel<<<B_ * N_, 256, 0, stream>>>(xT, L(l, 0), L(l, 1), L(l, 2),
                                                 L(l, 3), L(l, 4), A);
        node_kernel<<<B_, 320, 0, stream>>>(xT, A, L(l, 5), L(l, 6), L(l, 7),
                                            L(l, 8), L(l, 9),
                                            (float*)d_out, xT, (l == 0) ? 1 : 0);
    }
}

// Round 3
// 626.515 us; speedup vs baseline: 1.8860x; 1.8442x over previous
//
#include <hip/hip_runtime.h>
#include <math.h>

#define B_  128
#define N_  21
#define D_  300
#define NP  24

typedef __attribute__((ext_vector_type(8))) short short8v;
typedef __attribute__((ext_vector_type(4))) float f32x4;

__device__ __forceinline__ float lrelu(float v) { return v > 0.f ? v : 0.01f * v; }

// bf16 round-to-nearest-even split helpers (bit ops; matches HW cvt)
__device__ __forceinline__ unsigned short f2bf(float f) {
    unsigned u = __builtin_bit_cast(unsigned, f);
    u += 0x7FFFu + ((u >> 16) & 1u);
    return (unsigned short)(u >> 16);
}
__device__ __forceinline__ float bf2f(unsigned short h) {
    unsigned u = ((unsigned)h) << 16;
    return __builtin_bit_cast(float, u);
}

// ---------------------------------------------------------------------------
// Convert one layer's edge weights to bf16 hi/lo, row-major [out][in],
// w0 K padded 300->320 with zeros. blk layout (ushort offsets):
//   w0h @0 (81920), w0l @81920, w1h @163840 (32768), w1l @196608,
//   w2h @229376 (16384), w2l @245760.  Total 262144 ushorts = 512 KB.
__global__ __launch_bounds__(256) void prep_weights(
    const float* __restrict__ w0, const float* __restrict__ w1,
    const float* __restrict__ w2, unsigned short* __restrict__ blk)
{
    int idx = blockIdx.x * 256 + threadIdx.x;   // grid 512 -> 131072 exact
    float v; unsigned short *ph, *pl; int off;
    if (idx < 81920) {
        int n = idx / 320, k = idx - n * 320;
        v = (k < 300) ? w0[n * 300 + k] : 0.f;
        ph = blk; pl = blk + 81920; off = idx;
    } else if (idx < 114688) {
        int t = idx - 81920;
        v = w1[t];
        ph = blk + 163840; pl = blk + 196608; off = t;
    } else {
        int t = idx - 114688;
        v = w2[t];
        ph = blk + 229376; pl = blk + 245760; off = t;
    }
    unsigned short hb = f2bf(v);
    unsigned short lb = f2bf(v - bf2f(hb));
    ph[off] = hb; pl[off] = lb;
}

// ---------------------------------------------------------------------------
// Fused edge MLP via MFMA (bf16x3 split). Block = 32 pairs (M=32), 4 waves.
// Wave w: M-tile mt=w&1. G1: nt=(w>>1)*8+0..7 (N=256). G2/G3: nt=(w>>1)*4+0..3.
// LDS activations XOR-swizzled per 16B unit: unit u at row m -> u ^ (m&7).
__global__ __launch_bounds__(256) void edge_mfma(
    const float* __restrict__ x,
    const unsigned short* __restrict__ w0h, const unsigned short* __restrict__ w0l,
    const unsigned short* __restrict__ w1h, const unsigned short* __restrict__ w1l,
    const unsigned short* __restrict__ w2h, const unsigned short* __restrict__ w2l,
    const float* __restrict__ wo, const float* __restrict__ bo,
    float* __restrict__ adjraw)
{
    __shared__ __align__(16) unsigned short xh[32 * 64],  xl[32 * 64];
    __shared__ __align__(16) unsigned short h0h[32 * 256], h0l[32 * 256];
    __shared__ __align__(16) unsigned short h1h[32 * 128], h1l[32 * 128];
    __shared__ float h2s[32 * 132];
    __shared__ float s_wo[128];

    const int tid  = threadIdx.x;
    const int lane = tid & 63;
    const int w    = tid >> 6;
    const int l15  = lane & 15;
    const int l4   = lane >> 4;
    const int P0   = blockIdx.x * 32;

    if (tid < 128) s_wo[tid] = wo[tid];

    const int mt   = w & 1;
    const int am   = mt * 16 + l15;      // A-fragment row (pair), all 3 GEMMs
    const int aswz = am & 7;

    // staging coords: thread -> (pair row sm, k-oct sko)
    const int sm  = tid >> 3;
    const int sko = tid & 7;
    const float *xi, *xj;
    {
        int p = P0 + sm;
        int bb = p / 441;
        int rem = p - bb * 441;
        int ii = rem / 21;
        int jj = rem - ii * 21;
        xi = x + ((size_t)bb * N_ + ii) * D_;
        xj = x + ((size_t)bb * N_ + jj) * D_;
    }
    unsigned short* xhw = xh + sm * 64 + ((sko ^ (sm & 7)) << 3);
    unsigned short* xlw = xl + sm * 64 + ((sko ^ (sm & 7)) << 3);

    // ---------------- G1: h0[32][256] = xij[32][300] @ w0^T ----------------
    f32x4 acc[8];
    #pragma unroll
    for (int t = 0; t < 8; ++t) acc[t] = (f32x4){0.f, 0.f, 0.f, 0.f};

    const int ntb1 = (w >> 1) * 8;
    for (int c = 0; c < 5; ++c) {
        const int d0 = c * 64 + sko * 8;
        float v[8];
        if (d0 + 8 <= D_) {
            float4 a0 = *(const float4*)(xi + d0);
            float4 a1 = *(const float4*)(xi + d0 + 4);
            float4 b0 = *(const float4*)(xj + d0);
            float4 b1 = *(const float4*)(xj + d0 + 4);
            #pragma unroll
            for (int e = 0; e < 4; ++e) {
                v[e]     = expf(-fabsf((&a0.x)[e] - (&b0.x)[e]));
                v[4 + e] = expf(-fabsf((&a1.x)[e] - (&b1.x)[e]));
            }
        } else {
            #pragma unroll
            for (int e = 0; e < 8; ++e) {
                int d = d0 + e;
                v[e] = (d < D_) ? expf(-fabsf(xi[d] - xj[d])) : 0.f;
            }
        }
        short8v hv, lv;
        #pragma unroll
        for (int e = 0; e < 8; ++e) {
            unsigned short hb = f2bf(v[e]);
            unsigned short lb = f2bf(v[e] - bf2f(hb));
            hv[e] = (short)hb; lv[e] = (short)lb;
        }
        __syncthreads();                 // prev chunk fully consumed
        *(short8v*)xhw = hv;
        *(short8v*)xlw = lv;
        __syncthreads();                 // chunk visible

        #pragma unroll
        for (int ks = 0; ks < 2; ++ks) {
            const int u = ks * 4 + l4;
            short8v ah = *(const short8v*)(xh + am * 64 + ((u ^ aswz) << 3));
            short8v al = *(const short8v*)(xl + am * 64 + ((u ^ aswz) << 3));
            const int kg = c * 64 + ks * 32 + l4 * 8;
            #pragma unroll
            for (int t = 0; t < 8; ++t) {
                const int n = (ntb1 + t) * 16 + l15;
                short8v bh = *(const short8v*)(w0h + n * 320 + kg);
                short8v bl = *(const short8v*)(w0l + n * 320 + kg);
                acc[t] = __builtin_amdgcn_mfma_f32_16x16x32_bf16(ah, bh, acc[t], 0, 0, 0);
                acc[t] = __builtin_amdgcn_mfma_f32_16x16x32_bf16(ah, bl, acc[t], 0, 0, 0);
                acc[t] = __builtin_amdgcn_mfma_f32_16x16x32_bf16(al, bh, acc[t], 0, 0, 0);
            }
        }
    }
    // store h0 (lrelu + split); D layout: row=(l>>4)*4+r, col=l&15 per tile
    #pragma unroll
    for (int t = 0; t < 8; ++t) {
        const int co = (ntb1 + t) * 16 + l15;
        const int u0 = co >> 3, cr = co & 7;
        #pragma unroll
        for (int r = 0; r < 4; ++r) {
            const int mo = mt * 16 + l4 * 4 + r;
            float f = lrelu(acc[t][r]);
            unsigned short hb = f2bf(f);
            unsigned short lb = f2bf(f - bf2f(hb));
            const int off = mo * 256 + ((u0 ^ (mo & 7)) << 3) + cr;
            h0h[off] = hb; h0l[off] = lb;
        }
    }
    __syncthreads();

    // ---------------- G2: h1[32][128] = h0 @ w1^T, K=256 -------------------
    const int ntb2 = (w >> 1) * 4;
    f32x4 acc2[4];
    #pragma unroll
    for (int t = 0; t < 4; ++t) acc2[t] = (f32x4){0.f, 0.f, 0.f, 0.f};
    #pragma unroll
    for (int ks = 0; ks < 8; ++ks) {
        const int u = ks * 4 + l4;
        short8v ah = *(const short8v*)(h0h + am * 256 + ((u ^ aswz) << 3));
        short8v al = *(const short8v*)(h0l + am * 256 + ((u ^ aswz) << 3));
        const int kg = ks * 32 + l4 * 8;
        #pragma unroll
        for (int t = 0; t < 4; ++t) {
            const int n = (ntb2 + t) * 16 + l15;
            short8v bh = *(const short8v*)(w1h + n * 256 + kg);
            short8v bl = *(const short8v*)(w1l + n * 256 + kg);
            acc2[t] = __builtin_amdgcn_mfma_f32_16x16x32_bf16(ah, bh, acc2[t], 0, 0, 0);
            acc2[t] = __builtin_amdgcn_mfma_f32_16x16x32_bf16(ah, bl, acc2[t], 0, 0, 0);
            acc2[t] = __builtin_amdgcn_mfma_f32_16x16x32_bf16(al, bh, acc2[t], 0, 0, 0);
        }
    }
    #pragma unroll
    for (int t = 0; t < 4; ++t) {
        const int co = (ntb2 + t) * 16 + l15;
        const int u0 = co >> 3, cr = co & 7;
        #pragma unroll
        for (int r = 0; r < 4; ++r) {
            const int mo = mt * 16 + l4 * 4 + r;
            float f = lrelu(acc2[t][r]);
            unsigned short hb = f2bf(f);
            unsigned short lb = f2bf(f - bf2f(hb));
            const int off = mo * 128 + ((u0 ^ (mo & 7)) << 3) + cr;
            h1h[off] = hb; h1l[off] = lb;
        }
    }
    __syncthreads();

    // ---------------- G3: h2[32][128] = h1 @ w2^T, K=128 -------------------
    f32x4 acc3[4];
    #pragma unroll
    for (int t = 0; t < 4; ++t) acc3[t] = (f32x4){0.f, 0.f, 0.f, 0.f};
    #pragma unroll
    for (int ks = 0; ks < 4; ++ks) {
        const int u = ks * 4 + l4;
        short8v ah = *(const short8v*)(h1h + am * 128 + ((u ^ aswz) << 3));
        short8v al = *(const short8v*)(h1l + am * 128 + ((u ^ aswz) << 3));
        const int kg = ks * 32 + l4 * 8;
        #pragma unroll
        for (int t = 0; t < 4; ++t) {
            const int n = (ntb2 + t) * 16 + l15;
            short8v bh = *(const short8v*)(w2h + n * 128 + kg);
            short8v bl = *(const short8v*)(w2l + n * 128 + kg);
            acc3[t] = __builtin_amdgcn_mfma_f32_16x16x32_bf16(ah, bh, acc3[t], 0, 0, 0);
            acc3[t] = __builtin_amdgcn_mfma_f32_16x16x32_bf16(ah, bl, acc3[t], 0, 0, 0);
            acc3[t] = __builtin_amdgcn_mfma_f32_16x16x32_bf16(al, bh, acc3[t], 0, 0, 0);
        }
    }
    #pragma unroll
    for (int t = 0; t < 4; ++t) {
        const int co = (ntb2 + t) * 16 + l15;
        #pragma unroll
        for (int r = 0; r < 4; ++r) {
            const int mo = mt * 16 + l4 * 4 + r;
            h2s[mo * 132 + co] = lrelu(acc3[t][r]);
        }
    }
    __syncthreads();

    // ---------------- sim -> sigmoid -> zero diag -> adjraw ----------------
    {
        const int m = tid >> 3, sub = tid & 7;
        const float* hrow = h2s + m * 132 + sub * 16;
        const float* wrow = s_wo + sub * 16;
        float s = 0.f;
        #pragma unroll
        for (int cc = 0; cc < 16; ++cc) s += hrow[cc] * wrow[cc];
        s += __shfl_xor(s, 1);
        s += __shfl_xor(s, 2);
        s += __shfl_xor(s, 4);
        if (sub == 0) {
            s += bo[0];
            float a = 1.f / (1.f + expf(-s));
            int p = P0 + m;
            int bb = p / 441;
            int rem = p - bb * 441;
            int ii = rem / 21, jj = rem - ii * 21;
            if (ii == jj) a = 0.f;
            adjraw[p] = a;
        }
    }
}

// ---------------------------------------------------------------------------
// top-5 per row (lax.top_k tie-break: lowest index wins)
__global__ __launch_bounds__(64) void topk_kernel(
    const float* __restrict__ adjraw, float* __restrict__ A)
{
    const int row = blockIdx.x;
    const int lane = threadIdx.x;
    __shared__ float sadj[32];
    __shared__ unsigned s_used;
    if (lane < N_) sadj[lane] = adjraw[row * N_ + lane];
    __syncthreads();
    if (lane == 0) {
        unsigned used = 0;
        for (int r = 0; r < 5; ++r) {
            float best = -1.f; int bi = 0;
            for (int j = 0; j < N_; ++j) {
                if (used & (1u << j)) continue;
                if (sadj[j] > best) { best = sadj[j]; bi = j; }
            }
            used |= (1u << bi);
        }
        s_used = used;
    }
    __syncthreads();
    if (lane < N_)
        A[row * N_ + lane] = ((s_used >> lane) & 1u) ? sadj[lane] : 0.f;
}

// ---------------------------------------------------------------------------
// One block per b: fused node update (fp32, unchanged math from round 2).
// Stages x transposed in-kernel; reads+writes d_out in-place safely
// (block-local rows, barrier between stage and write).
__global__ __launch_bounds__(320) void node_kernel(
    const float* __restrict__ xin, const float* __restrict__ A,
    const float* __restrict__ wn, const float* __restrict__ bn,
    const float* __restrict__ wr, const float* __restrict__ br,
    const float* __restrict__ eemb, float* __restrict__ out)
{
    const int b = blockIdx.x;
    const int tid = threadIdx.x;
    __shared__ float sxT[D_][NP];
    __shared__ float sA[N_][NP];
    __shared__ float srs[N_];

    const float* xb = xin + (size_t)b * N_ * D_;
    for (int it = tid; it < D_ * NP; it += 320) {
        int d = it / NP, j = it - (it / NP) * NP;
        sxT[d][j] = (j < N_) ? xb[(size_t)j * D_ + d] : 0.f;
    }
    for (int it = tid; it < N_ * N_; it += 320) {
        int t = it / N_, s = it - (it / N_) * N_;
        sA[t][s] = A[((size_t)b * N_ + t) * N_ + s];
    }
    __syncthreads();
    if (tid < N_) {
        float s = 0.f;
        #pragma unroll
        for (int j = 0; j < N_; ++j) s += sA[tid][j];
        srs[tid] = s;
    }
    __syncthreads();

    const int o = tid;
    if (o < D_) {
        float nacc[NP], racc[NP];
        #pragma unroll
        for (int j = 0; j < NP; ++j) { nacc[j] = 0.f; racc[j] = 0.f; }
        const float* wnr = wn + (size_t)o * D_;
        const float* wrr = wr + (size_t)o * D_;
        for (int k4 = 0; k4 < D_; k4 += 4) {
            float4 wnv = *(const float4*)(wnr + k4);
            float4 wrv = *(const float4*)(wrr + k4);
            #pragma unroll
            for (int kk = 0; kk < 4; ++kk) {
                float wN = (&wnv.x)[kk], wR = (&wrv.x)[kk];
                const float* xr = &sxT[k4 + kk][0];
                #pragma unroll
                for (int j4 = 0; j4 < 6; ++j4) {
                    float4 xv = *(const float4*)(xr + j4 * 4);
                    #pragma unroll
                    for (int q = 0; q < 4; ++q) {
                        float xf = (&xv.x)[q];
                        nacc[j4 * 4 + q] += wN * xf;
                        racc[j4 * 4 + q] += wR * xf;
                    }
                }
            }
        }
        const float bn_o = bn[o], br_o = br[o], e0_o = eemb[o];
        #pragma unroll 1
        for (int t = 0; t < N_; ++t) {
            float m = 0.f;
            #pragma unroll
            for (int s = 0; s < N_; ++s) m += sA[t][s] * nacc[s];
            float val = lrelu((m + srs[t] * (bn_o + e0_o)) * 0.2f + racc[t] + br_o);
            out[((size_t)b * N_ + t) * D_ + o] = val;
        }
    }
}

// ---------------------------------------------------------------------------
extern "C" void kernel_launch(void* const* d_in, const int* in_sizes, int n_in,
                              void* d_out, int out_size, void* d_ws, size_t ws_size,
                              hipStream_t stream)
{
    const float* x0 = (const float*)d_in[0];
    auto L = [&](int l, int k) { return (const float*)d_in[1 + l * 10 + k]; };

    // ws layout: adjraw @0 (225,792 B), A @256 KB, weights @512 KB (2x 512 KB)
    float* adjraw = (float*)d_ws;
    float* A      = (float*)((char*)d_ws + 262144);
    unsigned short* wb = (unsigned short*)((char*)d_ws + 524288);

    for (int l = 0; l < 2; ++l) {
        unsigned short* blk = wb + (size_t)l * 262144;
        prep_weights<<<512, 256, 0, stream>>>(L(l, 0), L(l, 1), L(l, 2), blk);
    }
    for (int l = 0; l < 2; ++l) {
        const float* xin = (l == 0) ? x0 : (const float*)d_out;
        unsigned short* blk = wb + (size_t)l * 262144;
        edge_mfma<<<1764, 256, 0, stream>>>(xin,
            blk, blk + 81920, blk + 163840, blk + 196608, blk + 229376, blk + 245760,
            L(l, 3), L(l, 4), adjraw);
        topk_kernel<<<B_ * N_, 64, 0, stream>>>(adjraw, A);
        node_kernel<<<B_, 320, 0, stream>>>(xin, A, L(l, 5), L(l, 6), L(l, 7),
                                            L(l, 8), L(l, 9), (float*)d_out);
    }
}

// Round 4
// 470.150 us; speedup vs baseline: 2.5133x; 1.3326x over previous
//
#include <hip/hip_runtime.h>
#include <math.h>

#define B_  128
#define N_  21
#define D_  300
#define NPAIRS 231                 // upper-tri incl diag = 21*22/2
#define GRID_E ((B_ * NPAIRS) / 32)  // 924

typedef __attribute__((ext_vector_type(8))) short short8v;
typedef __attribute__((ext_vector_type(4))) short short4v;
typedef __attribute__((ext_vector_type(4))) float f32x4;

__device__ __forceinline__ float lrelu(float v) { return v > 0.f ? v : 0.01f * v; }

__device__ __forceinline__ unsigned short f2bf(float f) {
    unsigned u = __builtin_bit_cast(unsigned, f);
    u += 0x7FFFu + ((u >> 16) & 1u);
    return (unsigned short)(u >> 16);
}
__device__ __forceinline__ float bf2f(unsigned short h) {
    unsigned u = ((unsigned)h) << 16;
    return __builtin_bit_cast(float, u);
}

// ---------------------------------------------------------------------------
// Edge weights -> bf16 hi/lo, row-major [out][in], w0 K padded 300->320.
// blk (ushort offs): w0h@0(81920) w0l@81920 w1h@163840(32768) w1l@196608
//                    w2h@229376(16384) w2l@245760. 512 KB total.
__global__ __launch_bounds__(256) void prep_weights(
    const float* __restrict__ w0, const float* __restrict__ w1,
    const float* __restrict__ w2, unsigned short* __restrict__ blk)
{
    int idx = blockIdx.x * 256 + threadIdx.x;   // grid 512 -> 131072 exact
    float v; unsigned short *ph, *pl; int off;
    if (idx < 81920) {
        int n = idx / 320, k = idx - n * 320;
        v = (k < 300) ? w0[n * 300 + k] : 0.f;
        ph = blk; pl = blk + 81920; off = idx;
    } else if (idx < 114688) {
        int t = idx - 81920;
        v = w1[t];
        ph = blk + 163840; pl = blk + 196608; off = t;
    } else {
        int t = idx - 114688;
        v = w2[t];
        ph = blk + 229376; pl = blk + 245760; off = t;
    }
    unsigned short hb = f2bf(v);
    unsigned short lb = f2bf(v - bf2f(hb));
    ph[off] = hb; pl[off] = lb;
}

// ---------------------------------------------------------------------------
// Fused edge MLP, symmetric-dedup (upper-tri pairs), swapped MFMA operands:
//   mfma(a = weight frag, b = activation frag) -> C rows = channels,
//   cols = pairs  =>  packed b64 LDS stores + in-register sim reduction.
// Block = 32 pairs, 4 waves: pt = w&1 (pair tile), cq = w>>1 (channel half).
__global__ __launch_bounds__(256, 4) void edge_mfma(
    const float* __restrict__ x,
    const unsigned short* __restrict__ w0h, const unsigned short* __restrict__ w0l,
    const unsigned short* __restrict__ w1h, const unsigned short* __restrict__ w1l,
    const unsigned short* __restrict__ w2h, const unsigned short* __restrict__ w2l,
    const float* __restrict__ wo, const float* __restrict__ bo,
    float* __restrict__ adjraw)
{
    __shared__ __align__(16) union UU {
        struct { unsigned short h[2][1024], l[2][1024]; } xb;  // 8 KB (dbuf)
        struct { unsigned short h[4096], l[4096]; } h1;       // 16 KB
    } U;
    __shared__ __align__(16) unsigned short h0h[32 * 256], h0l[32 * 256]; // 32 KB
    __shared__ float s_wo[128];
    __shared__ float spart[2][32];

    const int tid  = threadIdx.x;
    const int lane = tid & 63;
    const int w    = tid >> 6;
    const int l15  = lane & 15;
    const int l4   = lane >> 4;
    const int P0   = blockIdx.x * 32;

    if (tid < 128) s_wo[tid] = wo[tid];

    const int pt = w & 1;
    const int cq = w >> 1;

    // staging coords: row sm (pair), k-quad sq
    const int sm = tid >> 3;
    const int sq = tid & 7;
    const float *xi, *xj;
    {
        int p = P0 + sm;
        int bb = p / NPAIRS;
        int u = p - bb * NPAIRS;
        int ii = 0;
        while (u >= N_ - ii) { u -= N_ - ii; ++ii; }
        int jj = ii + u;
        xi = x + ((size_t)bb * N_ + ii) * D_;
        xj = x + ((size_t)bb * N_ + jj) * D_;
    }
    const int xw_off = sm * 32 + (((sq >> 1) ^ ((sm >> 1) & 3)) << 3) + ((sq & 1) << 2);

    const int brow   = pt * 16 + l15;                 // pair row for B-frags
    const int xr_off = brow * 32 + ((l4 ^ ((brow >> 1) & 3)) << 3);
    const int bswz   = brow & 7;

    f32x4 acc[8];
    #pragma unroll
    for (int t = 0; t < 8; ++t) acc[t] = (f32x4){0.f, 0.f, 0.f, 0.f};

    auto stage = [&](int c, int sel) {
        const int d0 = c * 32 + sq * 4;
        short4v hv, lv;
        if (d0 < D_) {
            float4 xa = *(const float4*)(xi + d0);
            float4 xbv = *(const float4*)(xj + d0);
            #pragma unroll
            for (int e = 0; e < 4; ++e) {
                float v = expf(-fabsf((&xa.x)[e] - (&xbv.x)[e]));
                unsigned short hb = f2bf(v);
                hv[e] = (short)hb;
                lv[e] = (short)f2bf(v - bf2f(hb));
            }
        } else {
            hv = (short4v){0, 0, 0, 0};
            lv = (short4v){0, 0, 0, 0};
        }
        *(short4v*)(U.xb.h[sel] + xw_off) = hv;
        *(short4v*)(U.xb.l[sel] + xw_off) = lv;
    };

    stage(0, 0);
    __syncthreads();

    // ---------------- G1: h0^T = w0 @ xij^T, K=320 (10 chunks of 32) -------
    for (int c = 0; c < 10; ++c) {
        const int sel = c & 1;
        if (c < 9) stage(c + 1, sel ^ 1);
        short8v bh = *(const short8v*)(U.xb.h[sel] + xr_off);
        short8v bl = *(const short8v*)(U.xb.l[sel] + xr_off);
        const int kg = c * 32 + l4 * 8;
        #pragma unroll
        for (int t = 0; t < 8; ++t) {
            const int n = (cq * 8 + t) * 16 + l15;
            short8v ah = *(const short8v*)(w0h + (size_t)n * 320 + kg);
            short8v al = *(const short8v*)(w0l + (size_t)n * 320 + kg);
            acc[t] = __builtin_amdgcn_mfma_f32_16x16x32_bf16(ah, bh, acc[t], 0, 0, 0);
            acc[t] = __builtin_amdgcn_mfma_f32_16x16x32_bf16(ah, bl, acc[t], 0, 0, 0);
            acc[t] = __builtin_amdgcn_mfma_f32_16x16x32_bf16(al, bh, acc[t], 0, 0, 0);
        }
        __syncthreads();
    }

    // store h0[pair][chan]: lane holds 4 consecutive chans -> b64 packed
    #pragma unroll
    for (int t = 0; t < 8; ++t) {
        short4v hv, lv;
        #pragma unroll
        for (int r = 0; r < 4; ++r) {
            float f = lrelu(acc[t][r]);
            unsigned short hb = f2bf(f);
            hv[r] = (short)hb;
            lv[r] = (short)f2bf(f - bf2f(hb));
        }
        const int chanb = (cq * 8 + t) * 16 + l4 * 4;
        const int uo = (((chanb >> 3) ^ bswz) << 3) + ((l4 & 1) << 2);
        *(short4v*)(h0h + brow * 256 + uo) = hv;
        *(short4v*)(h0l + brow * 256 + uo) = lv;
    }
    __syncthreads();

    // ---------------- G2: h1^T = w1 @ h0^T, K=256 --------------------------
    f32x4 acc2[4];
    #pragma unroll
    for (int t = 0; t < 4; ++t) acc2[t] = (f32x4){0.f, 0.f, 0.f, 0.f};
    #pragma unroll
    for (int ks = 0; ks < 8; ++ks) {
        const int u = ks * 4 + l4;
        short8v bh = *(const short8v*)(h0h + brow * 256 + ((u ^ bswz) << 3));
        short8v bl = *(const short8v*)(h0l + brow * 256 + ((u ^ bswz) << 3));
        const int kg = ks * 32 + l4 * 8;
        #pragma unroll
        for (int t = 0; t < 4; ++t) {
            const int n = (cq * 4 + t) * 16 + l15;
            short8v ah = *(const short8v*)(w1h + (size_t)n * 256 + kg);
            short8v al = *(const short8v*)(w1l + (size_t)n * 256 + kg);
            acc2[t] = __builtin_amdgcn_mfma_f32_16x16x32_bf16(ah, bh, acc2[t], 0, 0, 0);
            acc2[t] = __builtin_amdgcn_mfma_f32_16x16x32_bf16(ah, bl, acc2[t], 0, 0, 0);
            acc2[t] = __builtin_amdgcn_mfma_f32_16x16x32_bf16(al, bh, acc2[t], 0, 0, 0);
        }
    }
    __syncthreads();   // all xb reads done (G1 loop) -> safe to write U.h1
    #pragma unroll
    for (int t = 0; t < 4; ++t) {
        short4v hv, lv;
        #pragma unroll
        for (int r = 0; r < 4; ++r) {
            float f = lrelu(acc2[t][r]);
            unsigned short hb = f2bf(f);
            hv[r] = (short)hb;
            lv[r] = (short)f2bf(f - bf2f(hb));
        }
        const int chanb = (cq * 4 + t) * 16 + l4 * 4;
        const int uo = (((chanb >> 3) ^ bswz) << 3) + ((l4 & 1) << 2);
        *(short4v*)(U.h1.h + brow * 128 + uo) = hv;
        *(short4v*)(U.h1.l + brow * 128 + uo) = lv;
    }
    __syncthreads();

    // ---------------- G3: h2^T = w2 @ h1^T, K=128 --------------------------
    f32x4 acc3[4];
    #pragma unroll
    for (int t = 0; t < 4; ++t) acc3[t] = (f32x4){0.f, 0.f, 0.f, 0.f};
    #pragma unroll
    for (int ks = 0; ks < 4; ++ks) {
        const int u = ks * 4 + l4;
        short8v bh = *(const short8v*)(U.h1.h + brow * 128 + ((u ^ bswz) << 3));
        short8v bl = *(const short8v*)(U.h1.l + brow * 128 + ((u ^ bswz) << 3));
        const int kg = ks * 32 + l4 * 8;
        #pragma unroll
        for (int t = 0; t < 4; ++t) {
            const int n = (cq * 4 + t) * 16 + l15;
            short8v ah = *(const short8v*)(w2h + (size_t)n * 128 + kg);
            short8v al = *(const short8v*)(w2l + (size_t)n * 128 + kg);
            acc3[t] = __builtin_amdgcn_mfma_f32_16x16x32_bf16(ah, bh, acc3[t], 0, 0, 0);
            acc3[t] = __builtin_amdgcn_mfma_f32_16x16x32_bf16(ah, bl, acc3[t], 0, 0, 0);
            acc3[t] = __builtin_amdgcn_mfma_f32_16x16x32_bf16(al, bh, acc3[t], 0, 0, 0);
        }
    }

    // ---------------- sim: in-register reduce over channels ----------------
    float ps = 0.f;
    #pragma unroll
    for (int t = 0; t < 4; ++t) {
        #pragma unroll
        for (int r = 0; r < 4; ++r) {
            const int chan = (cq * 4 + t) * 16 + l4 * 4 + r;
            ps += lrelu(acc3[t][r]) * s_wo[chan];
        }
    }
    ps += __shfl_xor(ps, 16);
    ps += __shfl_xor(ps, 32);
    if (l4 == 0) spart[cq][pt * 16 + l15] = ps;
    __syncthreads();

    if (tid < 32) {
        float sim = spart[0][tid] + spart[1][tid] + bo[0];
        float a = 1.f / (1.f + expf(-sim));
        int p = P0 + tid;
        int bb = p / NPAIRS;
        int u = p - bb * NPAIRS;
        int ii = 0;
        while (u >= N_ - ii) { u -= N_ - ii; ++ii; }
        int jj = ii + u;
        if (ii == jj) a = 0.f;
        adjraw[(size_t)bb * 441 + ii * 21 + jj] = a;
        adjraw[(size_t)bb * 441 + jj * 21 + ii] = a;
    }
}

// ---------------------------------------------------------------------------
// top-5 per row (lax.top_k tie-break: lowest index wins)
__global__ __launch_bounds__(64) void topk_kernel(
    const float* __restrict__ adjraw, float* __restrict__ A)
{
    const int row = blockIdx.x;
    const int lane = threadIdx.x;
    __shared__ float sadj[32];
    __shared__ unsigned s_used;
    if (lane < N_) sadj[lane] = adjraw[row * N_ + lane];
    __syncthreads();
    if (lane == 0) {
        unsigned used = 0;
        for (int r = 0; r < 5; ++r) {
            float best = -1.f; int bi = 0;
            for (int j = 0; j < N_; ++j) {
                if (used & (1u << j)) continue;
                if (sadj[j] > best) { best = sadj[j]; bi = j; }
            }
            used |= (1u << bi);
        }
        s_used = used;
    }
    __syncthreads();
    if (lane < N_)
        A[row * N_ + lane] = ((s_used >> lane) & 1u) ? sadj[lane] : 0.f;
}

// ---------------------------------------------------------------------------
// One block per b: fused node update (fp32). Coalesced natural-layout staging;
// in-place safe (block reads only its own b-slice into LDS before writing).
__global__ __launch_bounds__(320) void node_kernel(
    const float* __restrict__ xin, const float* __restrict__ A,
    const float* __restrict__ wn, const float* __restrict__ bn,
    const float* __restrict__ wr, const float* __restrict__ br,
    const float* __restrict__ eemb, float* __restrict__ out)
{
    const int b = blockIdx.x;
    const int tid = threadIdx.x;
    __shared__ float sx[N_][304];     // 25.5 KB, rows 16B-aligned
    __shared__ float sA[N_][24];
    __shared__ float srs[N_];

    const float* xb = xin + (size_t)b * N_ * D_;
    for (int it = tid; it < N_ * D_; it += 320) {
        int j = it / D_, d = it - (it / D_) * D_;
        sx[j][d] = xb[it];
    }
    for (int it = tid; it < N_ * N_; it += 320) {
        int t = it / N_, s = it - (it / N_) * N_;
        sA[t][s] = A[((size_t)b * N_ + t) * N_ + s];
    }
    __syncthreads();
    if (tid < N_) {
        float s = 0.f;
        #pragma unroll
        for (int j = 0; j < N_; ++j) s += sA[tid][j];
        srs[tid] = s;
    }
    __syncthreads();

    const int o = tid;
    if (o < D_) {
        float nacc[N_], racc[N_];
        #pragma unroll
        for (int j = 0; j < N_; ++j) { nacc[j] = 0.f; racc[j] = 0.f; }
        const float* wnr = wn + (size_t)o * D_;
        const float* wrr = wr + (size_t)o * D_;
        for (int k4 = 0; k4 < D_; k4 += 4) {
            float4 wn4 = *(const float4*)(wnr + k4);
            float4 wr4 = *(const float4*)(wrr + k4);
            #pragma unroll
            for (int j = 0; j < N_; ++j) {
                float4 xv = *(const float4*)(&sx[j][k4]);
                nacc[j] += wn4.x * xv.x; nacc[j] += wn4.y * xv.y;
                nacc[j] += wn4.z * xv.z; nacc[j] += wn4.w * xv.w;
                racc[j] += wr4.x * xv.x; racc[j] += wr4.y * xv.y;
                racc[j] += wr4.z * xv.z; racc[j] += wr4.w * xv.w;
            }
        }
        const float bn_o = bn[o], br_o = br[o], e0_o = eemb[o];
        const float add_o = bn_o + e0_o;
        #pragma unroll
        for (int t = 0; t < N_; ++t) {
            float m = 0.f;
            #pragma unroll
            for (int s = 0; s < N_; ++s) m += sA[t][s] * nacc[s];
            out[((size_t)b * N_ + t) * D_ + o] =
                lrelu((m + srs[t] * add_o) * 0.2f + racc[t] + br_o);
        }
    }
}

// ---------------------------------------------------------------------------
extern "C" void kernel_launch(void* const* d_in, const int* in_sizes, int n_in,
                              void* d_out, int out_size, void* d_ws, size_t ws_size,
                              hipStream_t stream)
{
    const float* x0 = (const float*)d_in[0];
    auto L = [&](int l, int k) { return (const float*)d_in[1 + l * 10 + k]; };

    // ws: adjraw @0 (226KB), A @256KB (226KB), weights @512KB (2 x 512KB)
    float* adjraw = (float*)d_ws;
    float* A      = (float*)((char*)d_ws + 262144);
    unsigned short* wb = (unsigned short*)((char*)d_ws + 524288);

    for (int l = 0; l < 2; ++l) {
        unsigned short* blk = wb + (size_t)l * 262144;
        prep_weights<<<512, 256, 0, stream>>>(L(l, 0), L(l, 1), L(l, 2), blk);
    }
    for (int l = 0; l < 2; ++l) {
        const float* xin = (l == 0) ? x0 : (const float*)d_out;
        unsigned short* blk = wb + (size_t)l * 262144;
        edge_mfma<<<GRID_E, 256, 0, stream>>>(xin,
            blk, blk + 81920, blk + 163840, blk + 196608, blk + 229376, blk + 245760,
            L(l, 3), L(l, 4), adjraw);
        topk_kernel<<<B_ * N_, 64, 0, stream>>>(adjraw, A);
        node_kernel<<<B_, 320, 0, stream>>>(xin, A, L(l, 5), L(l, 6), L(l, 7),
                                            L(l, 8), L(l, 9), (float*)d_out);
    }
}

// Round 5
// 334.131 us; speedup vs baseline: 3.5364x; 1.4071x over previous
//
#include <hip/hip_runtime.h>
#include <math.h>

#define B_  128
#define N_  21
#define D_  300
#define NPAIRS 231                 // upper-tri incl diag = 21*22/2
#define GRID_E ((B_ * NPAIRS) / 32)  // 924
#define NROWS (B_ * N_)            // 2688
#define DP  320                    // padded D for node GEMM

typedef __attribute__((ext_vector_type(8))) short short8v;
typedef __attribute__((ext_vector_type(4))) short short4v;
typedef __attribute__((ext_vector_type(4))) float f32x4;

__device__ __forceinline__ float lrelu(float v) { return v > 0.f ? v : 0.01f * v; }

__device__ __forceinline__ unsigned short f2bf(float f) {
    unsigned u = __builtin_bit_cast(unsigned, f);
    u += 0x7FFFu + ((u >> 16) & 1u);
    return (unsigned short)(u >> 16);
}
__device__ __forceinline__ float bf2f(unsigned short h) {
    unsigned u = ((unsigned)h) << 16;
    return __builtin_bit_cast(float, u);
}

// ---------------------------------------------------------------------------
// Edge weights -> bf16 hi/lo, row-major [out][in], w0 K padded 300->320.
// blk (ushort offs): w0h@0(81920) w0l@81920 w1h@163840(32768) w1l@196608
//                    w2h@229376(16384) w2l@245760. 512 KB total.
__global__ __launch_bounds__(256) void prep_weights(
    const float* __restrict__ w0, const float* __restrict__ w1,
    const float* __restrict__ w2, unsigned short* __restrict__ blk)
{
    int idx = blockIdx.x * 256 + threadIdx.x;   // grid 512 -> 131072 exact
    float v; unsigned short *ph, *pl; int off;
    if (idx < 81920) {
        int n = idx / 320, k = idx - n * 320;
        v = (k < 300) ? w0[n * 300 + k] : 0.f;
        ph = blk; pl = blk + 81920; off = idx;
    } else if (idx < 114688) {
        int t = idx - 81920;
        v = w1[t];
        ph = blk + 163840; pl = blk + 196608; off = t;
    } else {
        int t = idx - 114688;
        v = w2[t];
        ph = blk + 229376; pl = blk + 245760; off = t;
    }
    unsigned short hb = f2bf(v);
    unsigned short lb = f2bf(v - bf2f(hb));
    ph[off] = hb; pl[off] = lb;
}

// Node weights wn,wr -> bf16 hi/lo padded [320][320].
// blk: wnh@0(102400) wnl@102400 wrh@204800 wrl@307200 (ushorts)
__global__ __launch_bounds__(256) void prep_node(
    const float* __restrict__ wn, const float* __restrict__ wr,
    unsigned short* __restrict__ blk)
{
    int idx = blockIdx.x * 256 + threadIdx.x;   // grid 800 -> 204800 exact
    if (idx >= 204800) return;
    int mat = idx / 102400;
    int r = idx - mat * 102400;
    int n = r / 320, k = r - n * 320;
    const float* src = mat ? wr : wn;
    float v = (n < 300 && k < 300) ? src[n * 300 + k] : 0.f;
    unsigned short hb = f2bf(v);
    unsigned short lb = f2bf(v - bf2f(hb));
    blk[mat * 204800 + r] = hb;
    blk[mat * 204800 + 102400 + r] = lb;
}

// ---------------------------------------------------------------------------
// Fused edge MLP, symmetric dedup, swapped MFMA operands, register-batched
// weight loads (one vmcnt wait per chunk instead of 16 serial waits).
__global__ __launch_bounds__(256, 3) void edge_mfma(
    const float* __restrict__ x,
    const unsigned short* __restrict__ w0h, const unsigned short* __restrict__ w0l,
    const unsigned short* __restrict__ w1h, const unsigned short* __restrict__ w1l,
    const unsigned short* __restrict__ w2h, const unsigned short* __restrict__ w2l,
    const float* __restrict__ wo, const float* __restrict__ bo,
    float* __restrict__ adjraw)
{
    __shared__ __align__(16) union UU {
        struct { unsigned short h[2][1024], l[2][1024]; } xb;  // 8 KB (dbuf)
        struct { unsigned short h[4096], l[4096]; } h1;       // 16 KB
    } U;
    __shared__ __align__(16) unsigned short h0h[32 * 256], h0l[32 * 256]; // 32 KB
    __shared__ float s_wo[128];
    __shared__ float spart[2][32];

    const int tid  = threadIdx.x;
    const int lane = tid & 63;
    const int w    = tid >> 6;
    const int l15  = lane & 15;
    const int l4   = lane >> 4;
    const int P0   = blockIdx.x * 32;

    if (tid < 128) s_wo[tid] = wo[tid];

    const int pt = w & 1;
    const int cq = w >> 1;

    // staging coords: row sm (pair), k-quad sq
    const int sm = tid >> 3;
    const int sq = tid & 7;
    const float *xi, *xj;
    {
        int p = P0 + sm;
        int bb = p / NPAIRS;
        int u = p - bb * NPAIRS;
        int ii = 0;
        while (u >= N_ - ii) { u -= N_ - ii; ++ii; }
        int jj = ii + u;
        xi = x + ((size_t)bb * N_ + ii) * D_;
        xj = x + ((size_t)bb * N_ + jj) * D_;
    }
    const int xw_off = sm * 32 + (((sq >> 1) ^ ((sm >> 1) & 3)) << 3) + ((sq & 1) << 2);

    const int brow   = pt * 16 + l15;                 // pair row for B-frags
    const int xr_off = brow * 32 + ((l4 ^ ((brow >> 1) & 3)) << 3);
    const int bswz   = brow & 7;

    f32x4 acc[8];
    #pragma unroll
    for (int t = 0; t < 8; ++t) acc[t] = (f32x4){0.f, 0.f, 0.f, 0.f};

    // stage chunk 0 (d0 = sq*4 <= 28, always valid)
    {
        float4 xa = *(const float4*)(xi + sq * 4);
        float4 xbv = *(const float4*)(xj + sq * 4);
        short4v hv, lv;
        #pragma unroll
        for (int e = 0; e < 4; ++e) {
            float v = expf(-fabsf((&xa.x)[e] - (&xbv.x)[e]));
            unsigned short hb = f2bf(v);
            hv[e] = (short)hb;
            lv[e] = (short)f2bf(v - bf2f(hb));
        }
        *(short4v*)(U.xb.h[0] + xw_off) = hv;
        *(short4v*)(U.xb.l[0] + xw_off) = lv;
    }
    __syncthreads();

    // ---------------- G1: h0^T = w0 @ xij^T, K=320 (10 chunks of 32) -------
    const int ntb1 = cq * 8;
    #pragma unroll 1
    for (int c = 0; c < 10; ++c) {
        const int sel = c & 1;
        // 1) weight loads chunk c -> registers (batched, one wait)
        short8v wh[8], wl[8];
        const int kg = c * 32 + l4 * 8;
        #pragma unroll
        for (int t = 0; t < 8; ++t) {
            const size_t n = (size_t)((ntb1 + t) * 16 + l15);
            wh[t] = *(const short8v*)(w0h + n * 320 + kg);
            wl[t] = *(const short8v*)(w0l + n * 320 + kg);
        }
        // 2) x loads for chunk c+1 (issue early; consume after MFMAs)
        float4 xa, xbv;
        bool have = false;
        if (c < 9) {
            const int d0 = (c + 1) * 32 + sq * 4;
            if (d0 < D_) {
                xa = *(const float4*)(xi + d0);
                xbv = *(const float4*)(xj + d0);
                have = true;
            }
        }
        // 3) B-frags chunk c from LDS
        short8v bh = *(const short8v*)(U.xb.h[sel] + xr_off);
        short8v bl = *(const short8v*)(U.xb.l[sel] + xr_off);
        // 4) MFMA
        #pragma unroll
        for (int t = 0; t < 8; ++t) {
            acc[t] = __builtin_amdgcn_mfma_f32_16x16x32_bf16(wh[t], bh, acc[t], 0, 0, 0);
            acc[t] = __builtin_amdgcn_mfma_f32_16x16x32_bf16(wh[t], bl, acc[t], 0, 0, 0);
            acc[t] = __builtin_amdgcn_mfma_f32_16x16x32_bf16(wl[t], bh, acc[t], 0, 0, 0);
        }
        // 5) exp/cvt + ds_write staged chunk c+1 (after MFMAs)
        if (c < 9) {
            short4v hv = (short4v){0, 0, 0, 0}, lv = (short4v){0, 0, 0, 0};
            if (have) {
                #pragma unroll
                for (int e = 0; e < 4; ++e) {
                    float v = expf(-fabsf((&xa.x)[e] - (&xbv.x)[e]));
                    unsigned short hb = f2bf(v);
                    hv[e] = (short)hb;
                    lv[e] = (short)f2bf(v - bf2f(hb));
                }
            }
            *(short4v*)(U.xb.h[sel ^ 1] + xw_off) = hv;
            *(short4v*)(U.xb.l[sel ^ 1] + xw_off) = lv;
        }
        __syncthreads();
    }

    // store h0[pair][chan]: lane holds 4 consecutive chans -> b64 packed
    #pragma unroll
    for (int t = 0; t < 8; ++t) {
        short4v hv, lv;
        #pragma unroll
        for (int r = 0; r < 4; ++r) {
            float f = lrelu(acc[t][r]);
            unsigned short hb = f2bf(f);
            hv[r] = (short)hb;
            lv[r] = (short)f2bf(f - bf2f(hb));
        }
        const int chanb = (ntb1 + t) * 16 + l4 * 4;
        const int uo = (((chanb >> 3) ^ bswz) << 3) + ((l4 & 1) << 2);
        *(short4v*)(h0h + brow * 256 + uo) = hv;
        *(short4v*)(h0l + brow * 256 + uo) = lv;
    }
    __syncthreads();

    // ---------------- G2: h1^T = w1 @ h0^T, K=256 --------------------------
    const int ntb2 = cq * 4;
    f32x4 acc2[4];
    #pragma unroll
    for (int t = 0; t < 4; ++t) acc2[t] = (f32x4){0.f, 0.f, 0.f, 0.f};
    #pragma unroll
    for (int ks = 0; ks < 8; ++ks) {
        short8v wh[4], wl[4];
        const int kg = ks * 32 + l4 * 8;
        #pragma unroll
        for (int t = 0; t < 4; ++t) {
            const size_t n = (size_t)((ntb2 + t) * 16 + l15);
            wh[t] = *(const short8v*)(w1h + n * 256 + kg);
            wl[t] = *(const short8v*)(w1l + n * 256 + kg);
        }
        const int u = ks * 4 + l4;
        short8v bh = *(const short8v*)(h0h + brow * 256 + ((u ^ bswz) << 3));
        short8v bl = *(const short8v*)(h0l + brow * 256 + ((u ^ bswz) << 3));
        #pragma unroll
        for (int t = 0; t < 4; ++t) {
            acc2[t] = __builtin_amdgcn_mfma_f32_16x16x32_bf16(wh[t], bh, acc2[t], 0, 0, 0);
            acc2[t] = __builtin_amdgcn_mfma_f32_16x16x32_bf16(wh[t], bl, acc2[t], 0, 0, 0);
            acc2[t] = __builtin_amdgcn_mfma_f32_16x16x32_bf16(wl[t], bh, acc2[t], 0, 0, 0);
        }
    }
    __syncthreads();   // xb reads long done; safe to overwrite U with h1
    #pragma unroll
    for (int t = 0; t < 4; ++t) {
        short4v hv, lv;
        #pragma unroll
        for (int r = 0; r < 4; ++r) {
            float f = lrelu(acc2[t][r]);
            unsigned short hb = f2bf(f);
            hv[r] = (short)hb;
            lv[r] = (short)f2bf(f - bf2f(hb));
        }
        const int chanb = (ntb2 + t) * 16 + l4 * 4;
        const int uo = (((chanb >> 3) ^ bswz) << 3) + ((l4 & 1) << 2);
        *(short4v*)(U.h1.h + brow * 128 + uo) = hv;
        *(short4v*)(U.h1.l + brow * 128 + uo) = lv;
    }
    __syncthreads();

    // ---------------- G3: h2^T = w2 @ h1^T, K=128 --------------------------
    f32x4 acc3[4];
    #pragma unroll
    for (int t = 0; t < 4; ++t) acc3[t] = (f32x4){0.f, 0.f, 0.f, 0.f};
    #pragma unroll
    for (int ks = 0; ks < 4; ++ks) {
        short8v wh[4], wl[4];
        const int kg = ks * 32 + l4 * 8;
        #pragma unroll
        for (int t = 0; t < 4; ++t) {
            const size_t n = (size_t)((ntb2 + t) * 16 + l15);
            wh[t] = *(const short8v*)(w2h + n * 128 + kg);
            wl[t] = *(const short8v*)(w2l + n * 128 + kg);
        }
        const int u = ks * 4 + l4;
        short8v bh = *(const short8v*)(U.h1.h + brow * 128 + ((u ^ bswz) << 3));
        short8v bl = *(const short8v*)(U.h1.l + brow * 128 + ((u ^ bswz) << 3));
        #pragma unroll
        for (int t = 0; t < 4; ++t) {
            acc3[t] = __builtin_amdgcn_mfma_f32_16x16x32_bf16(wh[t], bh, acc3[t], 0, 0, 0);
            acc3[t] = __builtin_amdgcn_mfma_f32_16x16x32_bf16(wh[t], bl, acc3[t], 0, 0, 0);
            acc3[t] = __builtin_amdgcn_mfma_f32_16x16x32_bf16(wl[t], bh, acc3[t], 0, 0, 0);
        }
    }

    // ---------------- sim: in-register reduce over channels ----------------
    float ps = 0.f;
    #pragma unroll
    for (int t = 0; t < 4; ++t) {
        #pragma unroll
        for (int r = 0; r < 4; ++r) {
            const int chan = (ntb2 + t) * 16 + l4 * 4 + r;
            ps += lrelu(acc3[t][r]) * s_wo[chan];
        }
    }
    ps += __shfl_xor(ps, 16);
    ps += __shfl_xor(ps, 32);
    if (l4 == 0) spart[cq][pt * 16 + l15] = ps;
    __syncthreads();

    if (tid < 32) {
        float sim = spart[0][tid] + spart[1][tid] + bo[0];
        float a = 1.f / (1.f + expf(-sim));
        int p = P0 + tid;
        int bb = p / NPAIRS;
        int u = p - bb * NPAIRS;
        int ii = 0;
        while (u >= N_ - ii) { u -= N_ - ii; ++ii; }
        int jj = ii + u;
        if (ii == jj) a = 0.f;
        adjraw[(size_t)bb * 441 + ii * 21 + jj] = a;
        adjraw[(size_t)bb * 441 + jj * 21 + ii] = a;
    }
}

// ---------------------------------------------------------------------------
// top-5 per row (lax.top_k tie-break: lowest index wins)
__global__ __launch_bounds__(64) void topk_kernel(
    const float* __restrict__ adjraw, float* __restrict__ A)
{
    const int row = blockIdx.x;
    const int lane = threadIdx.x;
    __shared__ float sadj[32];
    __shared__ unsigned s_used;
    if (lane < N_) sadj[lane] = adjraw[row * N_ + lane];
    __syncthreads();
    if (lane == 0) {
        unsigned used = 0;
        for (int r = 0; r < 5; ++r) {
            float best = -1.f; int bi = 0;
            for (int j = 0; j < N_; ++j) {
                if (used & (1u << j)) continue;
                if (sadj[j] > best) { best = sadj[j]; bi = j; }
            }
            used |= (1u << bi);
        }
        s_used = used;
    }
    __syncthreads();
    if (lane < N_)
        A[row * N_ + lane] = ((s_used >> lane) & 1u) ? sadj[lane] : 0.f;
}

// ---------------------------------------------------------------------------
// Node GEMM via MFMA: P = x@wn^T and R = x@wr^T (no bias), M=2688 rows.
// grid (168, 2): blockIdx.x = 16-row tile, blockIdx.y = mat (0=wn,1=wr).
// 4 waves, each 5 n-tiles (80 cols). Output nbuf[mat][row][320] fp32.
__global__ __launch_bounds__(256, 4) void node_gemm(
    const float* __restrict__ xin,
    const unsigned short* __restrict__ wnh, const unsigned short* __restrict__ wnl,
    const unsigned short* __restrict__ wrh, const unsigned short* __restrict__ wrl,
    float* __restrict__ nbuf)
{
    __shared__ __align__(16) unsigned short sxh[2][512], sxl[2][512];  // 4 KB

    const int tid  = threadIdx.x;
    const int lane = tid & 63;
    const int w    = tid >> 6;
    const int l15  = lane & 15;
    const int l4   = lane >> 4;
    const int M0   = blockIdx.x * 16;
    const int mat  = blockIdx.y;

    const unsigned short* ah_base = mat ? wrh : wnh;
    const unsigned short* al_base = mat ? wrl : wnl;
    float* ob = nbuf + (size_t)mat * NROWS * DP;

    // staging coords: row sm (0..15), k-pair sk (even, 0..30)
    const int sm = tid >> 4;
    const int sk = (tid & 15) * 2;
    const float* xrow = xin + (size_t)(M0 + sm) * D_;
    const int sa = sm * 32 + (((sk >> 3) ^ ((sm >> 1) & 3)) << 3) + (sk & 7);

    const int xr_off = l15 * 32 + ((l4 ^ ((l15 >> 1) & 3)) << 3);

    f32x4 acc[5];
    #pragma unroll
    for (int t = 0; t < 5; ++t) acc[t] = (f32x4){0.f, 0.f, 0.f, 0.f};

    // stage chunk 0 (k0 = sk <= 30, valid)
    {
        float2 v = *(const float2*)(xrow + sk);
        unsigned short h0 = f2bf(v.x), h1 = f2bf(v.y);
        unsigned uh = (unsigned)h0 | ((unsigned)h1 << 16);
        unsigned ul = (unsigned)f2bf(v.x - bf2f(h0)) |
                      ((unsigned)f2bf(v.y - bf2f(h1)) << 16);
        *(unsigned*)(&sxh[0][sa]) = uh;
        *(unsigned*)(&sxl[0][sa]) = ul;
    }
    __syncthreads();

    #pragma unroll 1
    for (int c = 0; c < 10; ++c) {
        const int sel = c & 1;
        // weight loads chunk c -> registers
        short8v wh[5], wl[5];
        const int kg = c * 32 + l4 * 8;
        #pragma unroll
        for (int t = 0; t < 5; ++t) {
            const size_t n = (size_t)((w * 5 + t) * 16 + l15);
            wh[t] = *(const short8v*)(ah_base + n * DP + kg);
            wl[t] = *(const short8v*)(al_base + n * DP + kg);
        }
        // x loads for chunk c+1 (issue early)
        float2 xv; bool have = false;
        if (c < 9) {
            const int k0 = (c + 1) * 32 + sk;
            if (k0 < D_) { xv = *(const float2*)(xrow + k0); have = true; }
        }
        // B-frags chunk c
        short8v bh = *(const short8v*)(sxh[sel] + xr_off);
        short8v bl = *(const short8v*)(sxl[sel] + xr_off);
        #pragma unroll
        for (int t = 0; t < 5; ++t) {
            acc[t] = __builtin_amdgcn_mfma_f32_16x16x32_bf16(wh[t], bh, acc[t], 0, 0, 0);
            acc[t] = __builtin_amdgcn_mfma_f32_16x16x32_bf16(wh[t], bl, acc[t], 0, 0, 0);
            acc[t] = __builtin_amdgcn_mfma_f32_16x16x32_bf16(wl[t], bh, acc[t], 0, 0, 0);
        }
        // write staged chunk c+1
        if (c < 9) {
            unsigned uh = 0, ul = 0;
            if (have) {
                unsigned short h0 = f2bf(xv.x), h1 = f2bf(xv.y);
                uh = (unsigned)h0 | ((unsigned)h1 << 16);
                ul = (unsigned)f2bf(xv.x - bf2f(h0)) |
                     ((unsigned)f2bf(xv.y - bf2f(h1)) << 16);
            }
            *(unsigned*)(&sxh[sel ^ 1][sa]) = uh;
            *(unsigned*)(&sxl[sel ^ 1][sa]) = ul;
        }
        __syncthreads();
    }

    // store: lane holds rows n = tile*16 + l4*4 + r for m-row = M0 + l15
    #pragma unroll
    for (int t = 0; t < 5; ++t) {
        const int n0 = (w * 5 + t) * 16 + l4 * 4;
        float4 v;
        v.x = acc[t][0]; v.y = acc[t][1]; v.z = acc[t][2]; v.w = acc[t][3];
        *(float4*)(ob + (size_t)(M0 + l15) * DP + n0) = v;
    }
}

// ---------------------------------------------------------------------------
// Per-row combine: out = lrelu((A@P + rs*(bn+e0))*0.2 + R + br)
__global__ __launch_bounds__(256) void node_combine(
    const float* __restrict__ A, const float* __restrict__ nbuf,
    const float* __restrict__ bn, const float* __restrict__ br,
    const float* __restrict__ eemb, float* __restrict__ out)
{
    const int row = blockIdx.x;           // 0..2687
    const int b = row / N_;
    const int tid = threadIdx.x;
    __shared__ float sA[N_];
    __shared__ float s_rs;
    if (tid < N_) sA[tid] = A[(size_t)row * N_ + tid];
    __syncthreads();
    if (tid == 0) {
        float s = 0.f;
        #pragma unroll
        for (int j = 0; j < N_; ++j) s += sA[j];
        s_rs = s;
    }
    __syncthreads();
    const float* Pb = nbuf + (size_t)b * N_ * DP;
    const float* Rr = nbuf + (size_t)NROWS * DP + (size_t)row * DP;
    const float rs = s_rs;
    #pragma unroll
    for (int pass = 0; pass < 2; ++pass) {
        int o = tid + pass * 256;
        if (o < D_) {
            float m = 0.f;
            #pragma unroll
            for (int s = 0; s < N_; ++s) m += sA[s] * Pb[(size_t)s * DP + o];
            out[(size_t)row * D_ + o] =
                lrelu((m + rs * (bn[o] + eemb[o])) * 0.2f + Rr[o] + br[o]);
        }
    }
}

// ---------------------------------------------------------------------------
// Fallback fp32 node kernel (round-4, used if ws too small for nbuf)
__global__ __launch_bounds__(320) void node_kernel(
    const float* __restrict__ xin, const float* __restrict__ A,
    const float* __restrict__ wn, const float* __restrict__ bn,
    const float* __restrict__ wr, const float* __restrict__ br,
    const float* __restrict__ eemb, float* __restrict__ out)
{
    const int b = blockIdx.x;
    const int tid = threadIdx.x;
    __shared__ float sx[N_][304];
    __shared__ float sA[N_][24];
    __shared__ float srs[N_];

    const float* xb = xin + (size_t)b * N_ * D_;
    for (int it = tid; it < N_ * D_; it += 320) {
        int j = it / D_, d = it - (it / D_) * D_;
        sx[j][d] = xb[it];
    }
    for (int it = tid; it < N_ * N_; it += 320) {
        int t = it / N_, s = it - (it / N_) * N_;
        sA[t][s] = A[((size_t)b * N_ + t) * N_ + s];
    }
    __syncthreads();
    if (tid < N_) {
        float s = 0.f;
        #pragma unroll
        for (int j = 0; j < N_; ++j) s += sA[tid][j];
        srs[tid] = s;
    }
    __syncthreads();

    const int o = tid;
    if (o < D_) {
        float nacc[N_], racc[N_];
        #pragma unroll
        for (int j = 0; j < N_; ++j) { nacc[j] = 0.f; racc[j] = 0.f; }
        const float* wnr = wn + (size_t)o * D_;
        const float* wrr = wr + (size_t)o * D_;
        for (int k4 = 0; k4 < D_; k4 += 4) {
            float4 wn4 = *(const float4*)(wnr + k4);
            float4 wr4 = *(const float4*)(wrr + k4);
            #pragma unroll
            for (int j = 0; j < N_; ++j) {
                float4 xv = *(const float4*)(&sx[j][k4]);
                nacc[j] += wn4.x * xv.x; nacc[j] += wn4.y * xv.y;
                nacc[j] += wn4.z * xv.z; nacc[j] += wn4.w * xv.w;
                racc[j] += wr4.x * xv.x; racc[j] += wr4.y * xv.y;
                racc[j] += wr4.z * xv.z; racc[j] += wr4.w * xv.w;
            }
        }
        const float bn_o = bn[o], br_o = br[o], e0_o = eemb[o];
        const float add_o = bn_o + e0_o;
        #pragma unroll
        for (int t = 0; t < N_; ++t) {
            float m = 0.f;
            #pragma unroll
            for (int s = 0; s < N_; ++s) m += sA[t][s] * nacc[s];
            out[((size_t)b * N_ + t) * D_ + o] =
                lrelu((m + srs[t] * add_o) * 0.2f + racc[t] + br_o);
        }
    }
}

// ---------------------------------------------------------------------------
extern "C" void kernel_launch(void* const* d_in, const int* in_sizes, int n_in,
                              void* d_out, int out_size, void* d_ws, size_t ws_size,
                              hipStream_t stream)
{
    const float* x0 = (const float*)d_in[0];
    auto L = [&](int l, int k) { return (const float*)d_in[1 + l * 10 + k]; };

    // ws layout:
    //   adjraw @0        (225,792)
    //   A      @256KB    (225,792)
    //   edge w @512KB    (2 x 512KB)            -> ends 1,572,864
    //   node w @1.5MB    (2 x 819,200)          -> ends 3,211,264
    //   nbuf   @3,211,264 (2*2688*320*4 = 6,881,280) -> ends 10,092,544
    float* adjraw = (float*)d_ws;
    float* A      = (float*)((char*)d_ws + 262144);
    unsigned short* ewb = (unsigned short*)((char*)d_ws + 524288);
    unsigned short* nwb = (unsigned short*)((char*)d_ws + 1572864);
    float* nbuf   = (float*)((char*)d_ws + 3211264);
    const size_t WS_NEED = 10092544;
    const bool newnode = (ws_size >= WS_NEED);

    for (int l = 0; l < 2; ++l) {
        unsigned short* blk = ewb + (size_t)l * 262144;
        prep_weights<<<512, 256, 0, stream>>>(L(l, 0), L(l, 1), L(l, 2), blk);
        if (newnode)
            prep_node<<<800, 256, 0, stream>>>(L(l, 5), L(l, 7),
                                               nwb + (size_t)l * 409600);
    }
    for (int l = 0; l < 2; ++l) {
        const float* xin = (l == 0) ? x0 : (const float*)d_out;
        unsigned short* blk = ewb + (size_t)l * 262144;
        edge_mfma<<<GRID_E, 256, 0, stream>>>(xin,
            blk, blk + 81920, blk + 163840, blk + 196608, blk + 229376, blk + 245760,
            L(l, 3), L(l, 4), adjraw);
        topk_kernel<<<B_ * N_, 64, 0, stream>>>(adjraw, A);
        if (newnode) {
            unsigned short* nblk = nwb + (size_t)l * 409600;
            node_gemm<<<dim3(NROWS / 16, 2), 256, 0, stream>>>(
                xin, nblk, nblk + 102400, nblk + 204800, nblk + 307200, nbuf);
            node_combine<<<NROWS, 256, 0, stream>>>(A, nbuf, L(l, 6), L(l, 8),
                                                    L(l, 9), (float*)d_out);
        } else {
            node_kernel<<<B_, 320, 0, stream>>>(xin, A, L(l, 5), L(l, 6), L(l, 7),
                                                L(l, 8), L(l, 9), (float*)d_out);
        }
    }
}

// Round 6
// 328.629 us; speedup vs baseline: 3.5956x; 1.0167x over previous
//
#include <hip/hip_runtime.h>
#include <math.h>

#define B_  128
#define N_  21
#define D_  300
#define NPAIRS 231                  // upper-tri incl diag
#define NPAIR_TOT (B_ * NPAIRS)     // 29568
#define GRID_E (NPAIR_TOT / 64)     // 462 blocks x 4 waves x 16 pairs
#define NROWS (B_ * N_)             // 2688
#define DP  320

typedef __attribute__((ext_vector_type(8))) short short8v;
typedef __attribute__((ext_vector_type(4))) float f32x4;

__device__ __forceinline__ float lrelu(float v) { return v > 0.f ? v : 0.01f * v; }

__device__ __forceinline__ unsigned short f2bf(float f) {
    unsigned u = __builtin_bit_cast(unsigned, f);
    u += 0x7FFFu + ((u >> 16) & 1u);
    return (unsigned short)(u >> 16);
}
__device__ __forceinline__ float bf2f(unsigned short h) {
    unsigned u = ((unsigned)h) << 16;
    return __builtin_bit_cast(float, u);
}

// ---------------------------------------------------------------------------
// One prep kernel for everything: edge weights (2 layers) + node weights.
// edge blk (ushort offs per layer): w0h@0(81920) w0l@81920 w1h@163840(32768)
//   w1l@196608 w2h@229376(16384) w2l@245760 -> 262144 ushorts/layer.
// node blk per layer: wnh@0(102400) wnl@102400 wrh@204800 wrl@307200.
__global__ __launch_bounds__(256) void prep_all(
    const float* __restrict__ e00, const float* __restrict__ e01, const float* __restrict__ e02,
    const float* __restrict__ e10, const float* __restrict__ e11, const float* __restrict__ e12,
    const float* __restrict__ n0n, const float* __restrict__ n0r,
    const float* __restrict__ n1n, const float* __restrict__ n1r,
    unsigned short* __restrict__ ewb, unsigned short* __restrict__ nwb, int do_node)
{
    int idx = blockIdx.x * 256 + threadIdx.x;   // grid 2624 -> 671744 exact
    float v; unsigned short *ph, *pl; int off;
    if (idx < 262144) {
        int l = idx >> 17;                       // 0 or 1
        int t = idx & 131071;
        unsigned short* blk = ewb + (size_t)l * 262144;
        const float* w0 = l ? e10 : e00;
        const float* w1 = l ? e11 : e01;
        const float* w2 = l ? e12 : e02;
        if (t < 81920) {
            int n = t / 320, k = t - n * 320;
            v = (k < 300) ? w0[n * 300 + k] : 0.f;
            ph = blk; pl = blk + 81920; off = t;
        } else if (t < 114688) {
            int r = t - 81920; v = w1[r];
            ph = blk + 163840; pl = blk + 196608; off = r;
        } else {
            int r = t - 114688; v = w2[r];
            ph = blk + 229376; pl = blk + 245760; off = r;
        }
    } else {
        if (!do_node) return;
        int t = idx - 262144;                    // 0 .. 409599
        int l = t / 204800;
        int r = t - l * 204800;
        int mat = r / 102400;
        int q = r - mat * 102400;
        int n = q / 320, k = q - n * 320;
        const float* src = l ? (mat ? n1r : n1n) : (mat ? n0r : n0n);
        v = (n < 300 && k < 300) ? src[n * 300 + k] : 0.f;
        unsigned short* blk = nwb + (size_t)l * 409600;
        ph = blk + mat * 204800; pl = ph + 102400; off = q;
    }
    unsigned short hb = f2bf(v);
    ph[off] = hb; pl[off] = f2bf(v - bf2f(hb));
}

// ---------------------------------------------------------------------------
// 4-lane-group transpose: C-layout (chan = t*16+l4*4+r, pair = l15) ->
// B-frag (pair = l15, chans = ks*32+l4*8+e). tA/tB compile-time.
__device__ __forceinline__ short8v asm_frag(const uint2* arr, int tA, int tB,
                                            int s1, int s2, bool hi)
{
    unsigned a0 = (unsigned)__shfl((int)arr[tA].x, s1);
    unsigned b0 = (unsigned)__shfl((int)arr[tB].x, s1);
    unsigned a1 = (unsigned)__shfl((int)arr[tA].y, s1);
    unsigned b1 = (unsigned)__shfl((int)arr[tB].y, s1);
    unsigned a2 = (unsigned)__shfl((int)arr[tA].x, s2);
    unsigned b2 = (unsigned)__shfl((int)arr[tB].x, s2);
    unsigned a3 = (unsigned)__shfl((int)arr[tA].y, s2);
    unsigned b3 = (unsigned)__shfl((int)arr[tB].y, s2);
    union { unsigned u[4]; short8v v; } r;
    r.u[0] = hi ? b0 : a0; r.u[1] = hi ? b1 : a1;
    r.u[2] = hi ? b2 : a2; r.u[3] = hi ? b3 : a3;
    return r.v;
}

// ---------------------------------------------------------------------------
// Fully wave-independent edge MLP: 16 pairs per wave, zero LDS, zero barriers.
// All transposes via 4-lane shuffles; bf16x3 split math (identical numerics).
__global__ __launch_bounds__(256, 3) void edge_mfma(
    const float* __restrict__ x,
    const unsigned short* __restrict__ w0h, const unsigned short* __restrict__ w0l,
    const unsigned short* __restrict__ w1h, const unsigned short* __restrict__ w1l,
    const unsigned short* __restrict__ w2h, const unsigned short* __restrict__ w2l,
    const float* __restrict__ wo, const float* __restrict__ bo,
    float* __restrict__ adjraw)
{
    const int tid  = threadIdx.x;
    const int lane = tid & 63;
    const int w    = tid >> 6;
    const int l15  = lane & 15;
    const int l4   = lane >> 4;

    // this lane-column's pair
    const int p = (blockIdx.x * 4 + w) * 16 + l15;
    int bb = p / NPAIRS;
    int u  = p - bb * NPAIRS;
    int ii = 0;
    while (u >= N_ - ii) { u -= N_ - ii; ++ii; }
    int jj = ii + u;
    const float* xi = x + ((size_t)bb * N_ + ii) * D_;
    const float* xj = x + ((size_t)bb * N_ + jj) * D_;

    const int s1 = (lane & 15) | ((lane & 16) << 1);  // (p, 2*(l4&1))
    const int s2 = s1 + 16;                           // (p, 2*(l4&1)+1)
    const bool hi = (l4 >> 1) != 0;

    // ---------------- G1: h0 = w0 @ xij^T, K=320 ----------------
    f32x4 acc[16];
    #pragma unroll
    for (int t = 0; t < 16; ++t) acc[t] = (f32x4){0.f, 0.f, 0.f, 0.f};

    #pragma unroll 1
    for (int c = 0; c < 10; ++c) {
        const int d0 = c * 32 + l4 * 8;
        float v[8];
        if (c < 9) {
            float4 a0 = *(const float4*)(xi + d0);
            float4 a1 = *(const float4*)(xi + d0 + 4);
            float4 b0 = *(const float4*)(xj + d0);
            float4 b1 = *(const float4*)(xj + d0 + 4);
            #pragma unroll
            for (int e = 0; e < 4; ++e) {
                v[e]     = expf(-fabsf((&a0.x)[e] - (&b0.x)[e]));
                v[4 + e] = expf(-fabsf((&a1.x)[e] - (&b1.x)[e]));
            }
        } else {
            #pragma unroll
            for (int e = 0; e < 8; ++e) {
                int d = d0 + e;
                v[e] = (d < D_) ? expf(-fabsf(xi[d] - xj[d])) : 0.f;
            }
        }
        short8v bh, bl;
        #pragma unroll
        for (int e = 0; e < 8; ++e) {
            unsigned short hb = f2bf(v[e]);
            bh[e] = (short)hb;
            bl[e] = (short)f2bf(v[e] - bf2f(hb));
        }
        const int kg = c * 32 + l4 * 8;
        #pragma unroll
        for (int g = 0; g < 4; ++g) {
            short8v wh[4], wl[4];
            #pragma unroll
            for (int q = 0; q < 4; ++q) {
                const size_t n = (size_t)((g * 4 + q) * 16 + l15);
                wh[q] = *(const short8v*)(w0h + n * 320 + kg);
                wl[q] = *(const short8v*)(w0l + n * 320 + kg);
            }
            #pragma unroll
            for (int q = 0; q < 4; ++q) {
                acc[g*4+q] = __builtin_amdgcn_mfma_f32_16x16x32_bf16(wh[q], bh, acc[g*4+q], 0, 0, 0);
                acc[g*4+q] = __builtin_amdgcn_mfma_f32_16x16x32_bf16(wh[q], bl, acc[g*4+q], 0, 0, 0);
                acc[g*4+q] = __builtin_amdgcn_mfma_f32_16x16x32_bf16(wl[q], bh, acc[g*4+q], 0, 0, 0);
            }
        }
    }

    // pack h0 -> bf16 hi/lo (lane keeps chans t*16+l4*4+r for its pair col)
    uint2 hh[16], ll[16];
    #pragma unroll
    for (int t = 0; t < 16; ++t) {
        unsigned short h_[4], l_[4];
        #pragma unroll
        for (int r = 0; r < 4; ++r) {
            float f = lrelu(acc[t][r]);
            h_[r] = f2bf(f);
            l_[r] = f2bf(f - bf2f(h_[r]));
        }
        hh[t].x = (unsigned)h_[0] | ((unsigned)h_[1] << 16);
        hh[t].y = (unsigned)h_[2] | ((unsigned)h_[3] << 16);
        ll[t].x = (unsigned)l_[0] | ((unsigned)l_[1] << 16);
        ll[t].y = (unsigned)l_[2] | ((unsigned)l_[3] << 16);
    }

    // ---------------- G2: h1 = w1 @ h0^T, K=256 ----------------
    f32x4 acc2[8];
    #pragma unroll
    for (int t = 0; t < 8; ++t) acc2[t] = (f32x4){0.f, 0.f, 0.f, 0.f};
    #pragma unroll
    for (int ks = 0; ks < 8; ++ks) {
        short8v bh = asm_frag(hh, 2*ks, 2*ks+1, s1, s2, hi);
        short8v bl = asm_frag(ll, 2*ks, 2*ks+1, s1, s2, hi);
        const int kg = ks * 32 + l4 * 8;
        #pragma unroll
        for (int g = 0; g < 4; ++g) {
            short8v wh[2], wl[2];
            #pragma unroll
            for (int q = 0; q < 2; ++q) {
                const size_t n = (size_t)((g * 2 + q) * 16 + l15);
                wh[q] = *(const short8v*)(w1h + n * 256 + kg);
                wl[q] = *(const short8v*)(w1l + n * 256 + kg);
            }
            #pragma unroll
            for (int q = 0; q < 2; ++q) {
                acc2[g*2+q] = __builtin_amdgcn_mfma_f32_16x16x32_bf16(wh[q], bh, acc2[g*2+q], 0, 0, 0);
                acc2[g*2+q] = __builtin_amdgcn_mfma_f32_16x16x32_bf16(wh[q], bl, acc2[g*2+q], 0, 0, 0);
                acc2[g*2+q] = __builtin_amdgcn_mfma_f32_16x16x32_bf16(wl[q], bh, acc2[g*2+q], 0, 0, 0);
            }
        }
    }

    // pack h1
    uint2 hh1[8], ll1[8];
    #pragma unroll
    for (int t = 0; t < 8; ++t) {
        unsigned short h_[4], l_[4];
        #pragma unroll
        for (int r = 0; r < 4; ++r) {
            float f = lrelu(acc2[t][r]);
            h_[r] = f2bf(f);
            l_[r] = f2bf(f - bf2f(h_[r]));
        }
        hh1[t].x = (unsigned)h_[0] | ((unsigned)h_[1] << 16);
        hh1[t].y = (unsigned)h_[2] | ((unsigned)h_[3] << 16);
        ll1[t].x = (unsigned)l_[0] | ((unsigned)l_[1] << 16);
        ll1[t].y = (unsigned)l_[2] | ((unsigned)l_[3] << 16);
    }

    // ---------------- G3: h2 = w2 @ h1^T, K=128 ----------------
    f32x4 acc3[8];
    #pragma unroll
    for (int t = 0; t < 8; ++t) acc3[t] = (f32x4){0.f, 0.f, 0.f, 0.f};
    #pragma unroll
    for (int ks = 0; ks < 4; ++ks) {
        short8v bh = asm_frag(hh1, 2*ks, 2*ks+1, s1, s2, hi);
        short8v bl = asm_frag(ll1, 2*ks, 2*ks+1, s1, s2, hi);
        const int kg = ks * 32 + l4 * 8;
        #pragma unroll
        for (int g = 0; g < 4; ++g) {
            short8v wh[2], wl[2];
            #pragma unroll
            for (int q = 0; q < 2; ++q) {
                const size_t n = (size_t)((g * 2 + q) * 16 + l15);
                wh[q] = *(const short8v*)(w2h + n * 128 + kg);
                wl[q] = *(const short8v*)(w2l + n * 128 + kg);
            }
            #pragma unroll
            for (int q = 0; q < 2; ++q) {
                acc3[g*2+q] = __builtin_amdgcn_mfma_f32_16x16x32_bf16(wh[q], bh, acc3[g*2+q], 0, 0, 0);
                acc3[g*2+q] = __builtin_amdgcn_mfma_f32_16x16x32_bf16(wh[q], bl, acc3[g*2+q], 0, 0, 0);
                acc3[g*2+q] = __builtin_amdgcn_mfma_f32_16x16x32_bf16(wl[q], bh, acc3[g*2+q], 0, 0, 0);
            }
        }
    }

    // ---------------- sim: in-register reduce over 128 channels ------------
    float ps = 0.f;
    #pragma unroll
    for (int t = 0; t < 8; ++t) {
        float4 wov = *(const float4*)(wo + t * 16 + l4 * 4);
        #pragma unroll
        for (int r = 0; r < 4; ++r)
            ps += lrelu(acc3[t][r]) * (&wov.x)[r];
    }
    ps += __shfl_xor(ps, 16);
    ps += __shfl_xor(ps, 32);
    if (l4 == 0) {
        float a = 1.f / (1.f + expf(-(ps + bo[0])));
        if (ii == jj) a = 0.f;
        adjraw[(size_t)bb * 441 + ii * 21 + jj] = a;
        adjraw[(size_t)bb * 441 + jj * 21 + ii] = a;
    }
}

// ---------------------------------------------------------------------------
// top-5 per row (fallback path only)
__global__ __launch_bounds__(64) void topk_kernel(
    const float* __restrict__ adjraw, float* __restrict__ A)
{
    const int row = blockIdx.x;
    const int lane = threadIdx.x;
    __shared__ float sadj[32];
    __shared__ unsigned s_used;
    if (lane < N_) sadj[lane] = adjraw[row * N_ + lane];
    __syncthreads();
    if (lane == 0) {
        unsigned used = 0;
        for (int r = 0; r < 5; ++r) {
            float best = -1.f; int bi = 0;
            for (int j = 0; j < N_; ++j) {
                if (used & (1u << j)) continue;
                if (sadj[j] > best) { best = sadj[j]; bi = j; }
            }
            used |= (1u << bi);
        }
        s_used = used;
    }
    __syncthreads();
    if (lane < N_)
        A[row * N_ + lane] = ((s_used >> lane) & 1u) ? sadj[lane] : 0.f;
}

// ---------------------------------------------------------------------------
// Node GEMM via MFMA: P = x@wn^T and R = x@wr^T, M=2688 rows (unchanged).
__global__ __launch_bounds__(256, 4) void node_gemm(
    const float* __restrict__ xin,
    const unsigned short* __restrict__ wnh, const unsigned short* __restrict__ wnl,
    const unsigned short* __restrict__ wrh, const unsigned short* __restrict__ wrl,
    float* __restrict__ nbuf)
{
    __shared__ __align__(16) unsigned short sxh[2][512], sxl[2][512];

    const int tid  = threadIdx.x;
    const int lane = tid & 63;
    const int w    = tid >> 6;
    const int l15  = lane & 15;
    const int l4   = lane >> 4;
    const int M0   = blockIdx.x * 16;
    const int mat  = blockIdx.y;

    const unsigned short* ah_base = mat ? wrh : wnh;
    const unsigned short* al_base = mat ? wrl : wnl;
    float* ob = nbuf + (size_t)mat * NROWS * DP;

    const int sm = tid >> 4;
    const int sk = (tid & 15) * 2;
    const float* xrow = xin + (size_t)(M0 + sm) * D_;
    const int sa = sm * 32 + (((sk >> 3) ^ ((sm >> 1) & 3)) << 3) + (sk & 7);
    const int xr_off = l15 * 32 + ((l4 ^ ((l15 >> 1) & 3)) << 3);

    f32x4 acc[5];
    #pragma unroll
    for (int t = 0; t < 5; ++t) acc[t] = (f32x4){0.f, 0.f, 0.f, 0.f};

    {
        float2 v = *(const float2*)(xrow + sk);
        unsigned short h0 = f2bf(v.x), h1 = f2bf(v.y);
        unsigned uh = (unsigned)h0 | ((unsigned)h1 << 16);
        unsigned ul = (unsigned)f2bf(v.x - bf2f(h0)) |
                      ((unsigned)f2bf(v.y - bf2f(h1)) << 16);
        *(unsigned*)(&sxh[0][sa]) = uh;
        *(unsigned*)(&sxl[0][sa]) = ul;
    }
    __syncthreads();

    #pragma unroll 1
    for (int c = 0; c < 10; ++c) {
        const int sel = c & 1;
        short8v wh[5], wl[5];
        const int kg = c * 32 + l4 * 8;
        #pragma unroll
        for (int t = 0; t < 5; ++t) {
            const size_t n = (size_t)((w * 5 + t) * 16 + l15);
            wh[t] = *(const short8v*)(ah_base + n * DP + kg);
            wl[t] = *(const short8v*)(al_base + n * DP + kg);
        }
        float2 xv; bool have = false;
        if (c < 9) {
            const int k0 = (c + 1) * 32 + sk;
            if (k0 < D_) { xv = *(const float2*)(xrow + k0); have = true; }
        }
        short8v bh = *(const short8v*)(sxh[sel] + xr_off);
        short8v bl = *(const short8v*)(sxl[sel] + xr_off);
        #pragma unroll
        for (int t = 0; t < 5; ++t) {
            acc[t] = __builtin_amdgcn_mfma_f32_16x16x32_bf16(wh[t], bh, acc[t], 0, 0, 0);
            acc[t] = __builtin_amdgcn_mfma_f32_16x16x32_bf16(wh[t], bl, acc[t], 0, 0, 0);
            acc[t] = __builtin_amdgcn_mfma_f32_16x16x32_bf16(wl[t], bh, acc[t], 0, 0, 0);
        }
        if (c < 9) {
            unsigned uh = 0, ul = 0;
            if (have) {
                unsigned short h0 = f2bf(xv.x), h1 = f2bf(xv.y);
                uh = (unsigned)h0 | ((unsigned)h1 << 16);
                ul = (unsigned)f2bf(xv.x - bf2f(h0)) |
                     ((unsigned)f2bf(xv.y - bf2f(h1)) << 16);
            }
            *(unsigned*)(&sxh[sel ^ 1][sa]) = uh;
            *(unsigned*)(&sxl[sel ^ 1][sa]) = ul;
        }
        __syncthreads();
    }

    #pragma unroll
    for (int t = 0; t < 5; ++t) {
        const int n0 = (w * 5 + t) * 16 + l4 * 4;
        float4 v;
        v.x = acc[t][0]; v.y = acc[t][1]; v.z = acc[t][2]; v.w = acc[t][3];
        *(float4*)(ob + (size_t)(M0 + l15) * DP + n0) = v;
    }
}

// ---------------------------------------------------------------------------
// Fused top-k + combine: out = lrelu((A@P + rs*(bn+e0))*0.2 + R + br)
__global__ __launch_bounds__(256) void node_combine(
    const float* __restrict__ adjraw, const float* __restrict__ nbuf,
    const float* __restrict__ bn, const float* __restrict__ br,
    const float* __restrict__ eemb, float* __restrict__ out)
{
    const int row = blockIdx.x;           // 0..2687
    const int b = row / N_;
    const int tid = threadIdx.x;
    __shared__ float sadj[24];
    __shared__ float sA[24];
    __shared__ float s_rs;
    if (tid < N_) sadj[tid] = adjraw[(size_t)row * N_ + tid];
    __syncthreads();
    if (tid == 0) {
        unsigned used = 0;
        for (int r = 0; r < 5; ++r) {
            float best = -1.f; int bi = 0;
            for (int j = 0; j < N_; ++j) {
                if (used & (1u << j)) continue;
                if (sadj[j] > best) { best = sadj[j]; bi = j; }
            }
            used |= (1u << bi);
        }
        float rs = 0.f;
        for (int j = 0; j < N_; ++j) {
            float m = ((used >> j) & 1u) ? sadj[j] : 0.f;
            sA[j] = m; rs += m;
        }
        s_rs = rs;
    }
    __syncthreads();
    const float* Pb = nbuf + (size_t)b * N_ * DP;
    const float* Rr = nbuf + (size_t)NROWS * DP + (size_t)row * DP;
    const float rs = s_rs;
    #pragma unroll
    for (int pass = 0; pass < 2; ++pass) {
        int o = tid + pass * 256;
        if (o < D_) {
            float m = 0.f;
            #pragma unroll
            for (int s = 0; s < N_; ++s) m += sA[s] * Pb[(size_t)s * DP + o];
            out[(size_t)row * D_ + o] =
                lrelu((m + rs * (bn[o] + eemb[o])) * 0.2f + Rr[o] + br[o]);
        }
    }
}

// ---------------------------------------------------------------------------
// Fallback fp32 node kernel (if ws too small for nbuf)
__global__ __launch_bounds__(320) void node_kernel(
    const float* __restrict__ xin, const float* __restrict__ A,
    const float* __restrict__ wn, const float* __restrict__ bn,
    const float* __restrict__ wr, const float* __restrict__ br,
    const float* __restrict__ eemb, float* __restrict__ out)
{
    const int b = blockIdx.x;
    const int tid = threadIdx.x;
    __shared__ float sx[N_][304];
    __shared__ float sA[N_][24];
    __shared__ float srs[N_];

    const float* xb = xin + (size_t)b * N_ * D_;
    for (int it = tid; it < N_ * D_; it += 320) {
        int j = it / D_, d = it - (it / D_) * D_;
        sx[j][d] = xb[it];
    }
    for (int it = tid; it < N_ * N_; it += 320) {
        int t = it / N_, s = it - (it / N_) * N_;
        sA[t][s] = A[((size_t)b * N_ + t) * N_ + s];
    }
    __syncthreads();
    if (tid < N_) {
        float s = 0.f;
        #pragma unroll
        for (int j = 0; j < N_; ++j) s += sA[tid][j];
        srs[tid] = s;
    }
    __syncthreads();

    const int o = tid;
    if (o < D_) {
        float nacc[N_], racc[N_];
        #pragma unroll
        for (int j = 0; j < N_; ++j) { nacc[j] = 0.f; racc[j] = 0.f; }
        const float* wnr = wn + (size_t)o * D_;
        const float* wrr = wr + (size_t)o * D_;
        for (int k4 = 0; k4 < D_; k4 += 4) {
            float4 wn4 = *(const float4*)(wnr + k4);
            float4 wr4 = *(const float4*)(wrr + k4);
            #pragma unroll
            for (int j = 0; j < N_; ++j) {
                float4 xv = *(const float4*)(&sx[j][k4]);
                nacc[j] += wn4.x * xv.x; nacc[j] += wn4.y * xv.y;
                nacc[j] += wn4.z * xv.z; nacc[j] += wn4.w * xv.w;
                racc[j] += wr4.x * xv.x; racc[j] += wr4.y * xv.y;
                racc[j] += wr4.z * xv.z; racc[j] += wr4.w * xv.w;
            }
        }
        const float bn_o = bn[o], br_o = br[o], e0_o = eemb[o];
        const float add_o = bn_o + e0_o;
        #pragma unroll
        for (int t = 0; t < N_; ++t) {
            float m = 0.f;
            #pragma unroll
            for (int s = 0; s < N_; ++s) m += sA[t][s] * nacc[s];
            out[((size_t)b * N_ + t) * D_ + o] =
                lrelu((m + srs[t] * add_o) * 0.2f + racc[t] + br_o);
        }
    }
}

// ---------------------------------------------------------------------------
extern "C" void kernel_launch(void* const* d_in, const int* in_sizes, int n_in,
                              void* d_out, int out_size, void* d_ws, size_t ws_size,
                              hipStream_t stream)
{
    const float* x0 = (const float*)d_in[0];
    auto L = [&](int l, int k) { return (const float*)d_in[1 + l * 10 + k]; };

    // ws layout:
    //   adjraw @0        (225,792)
    //   A      @256KB    (225,792)               (fallback only)
    //   edge w @512KB    (2 x 512KB)             -> ends 1,572,864
    //   node w @1.5MB    (2 x 819,200)           -> ends 3,211,264
    //   nbuf   @3,211,264 (6,881,280)            -> ends 10,092,544
    float* adjraw = (float*)d_ws;
    float* A      = (float*)((char*)d_ws + 262144);
    unsigned short* ewb = (unsigned short*)((char*)d_ws + 524288);
    unsigned short* nwb = (unsigned short*)((char*)d_ws + 1572864);
    float* nbuf   = (float*)((char*)d_ws + 3211264);
    const size_t WS_NEED = 10092544;
    const bool newnode = (ws_size >= WS_NEED);

    prep_all<<<2624, 256, 0, stream>>>(
        L(0,0), L(0,1), L(0,2), L(1,0), L(1,1), L(1,2),
        L(0,5), L(0,7), L(1,5), L(1,7), ewb, nwb, newnode ? 1 : 0);

    for (int l = 0; l < 2; ++l) {
        const float* xin = (l == 0) ? x0 : (const float*)d_out;
        unsigned short* blk = ewb + (size_t)l * 262144;
        edge_mfma<<<GRID_E, 256, 0, stream>>>(xin,
            blk, blk + 81920, blk + 163840, blk + 196608, blk + 229376, blk + 245760,
            L(l, 3), L(l, 4), adjraw);
        if (newnode) {
            unsigned short* nblk = nwb + (size_t)l * 409600;
            node_gemm<<<dim3(NROWS / 16, 2), 256, 0, stream>>>(
                xin, nblk, nblk + 102400, nblk + 204800, nblk + 307200, nbuf);
            node_combine<<<NROWS, 256, 0, stream>>>(adjraw, nbuf, L(l, 6), L(l, 8),
                                                    L(l, 9), (float*)d_out);
        } else {
            topk_kernel<<<NROWS, 64, 0, stream>>>(adjraw, A);
            node_kernel<<<B_, 320, 0, stream>>>(xin, A, L(l, 5), L(l, 6), L(l, 7),
                                                L(l, 8), L(l, 9), (float*)d_out);
        }
    }
}